// Round 4
// baseline (1138.514 us; speedup 1.0000x reference)
//
#include <hip/hip_runtime.h>
#include <math.h>

#define N_USERS 8192
#define DIMS    128
#define EDGES   262144
#define KCAND   131072
#define NTOT    (EDGES + KCAND)      // 393216
#define QCAP    48                   // per-(row,quarter) candidate capacity
#define NCELLS  (N_USERS * 4)        // 32768 (row, quarter) cells
#define COS_THR 0.3f

// ---------------------------------------------------------------------------
// 1) normalize — bit-exact vs numpy (pairwise 8-acc + tree, double sqrt).
// ---------------------------------------------------------------------------
__global__ __launch_bounds__(256) void normalize_k(const float* __restrict__ x,
                                                   float* __restrict__ u) {
#pragma clang fp contract(off)
  int i = blockIdx.x * 256 + threadIdx.x;
  if (i >= N_USERS) return;
  const float* r = x + (size_t)i * DIMS;
  float a[8];
#pragma unroll
  for (int j = 0; j < 8; ++j) { float t = r[j]; a[j] = t * t; }
  for (int b8 = 8; b8 < DIMS; b8 += 8) {
#pragma unroll
    for (int j = 0; j < 8; ++j) { float t = r[b8 + j]; a[j] = a[j] + t * t; }
  }
  float s = ((a[0] + a[1]) + (a[2] + a[3])) + ((a[4] + a[5]) + (a[6] + a[7]));
  float n = (float)sqrt((double)s);
  n = fmaxf(n, 1e-12f);
  for (int k = 0; k < DIMS; ++k) u[(size_t)i * DIMS + k] = r[k] / n;
}

// ---------------------------------------------------------------------------
// 1b) repack A for wave-uniform scalar loads:
//     Ap[rb (256)][k4 (32)][row (32)][kk (4)]  = u[rb*32+row][k4*4+kk]
//     A wave's per-k4 slice (8 rows x 4 ks) is 128 B contiguous.
// ---------------------------------------------------------------------------
__global__ __launch_bounds__(256) void repack_A(const float* __restrict__ u,
                                                float* __restrict__ Ap) {
  int rb = blockIdx.x, tid = threadIdx.x;
#pragma unroll
  for (int it = 0; it < 4; ++it) {
    int idx = it * 256 + tid;          // 0..1023 float4s
    int row = idx >> 5;                // 0..31
    int k4  = idx & 31;                // 0..31
    float4 f = *(const float4*)(u + ((size_t)rb * 32 + row) * DIMS + k4 * 4);
    *(float4*)(Ap + (((size_t)rb * 32 + k4) * 32 + row) * 4) = f;
  }
}

// ---------------------------------------------------------------------------
// 2) exclusion bitmask from nonzero_idx (8192 x 256 words)
// ---------------------------------------------------------------------------
__global__ __launch_bounds__(256) void build_excl(const int* __restrict__ nz,
                                                  unsigned* __restrict__ excl) {
  int t = blockIdx.x * 256 + threadIdx.x;
  if (t >= EDGES) return;
  int i = nz[2 * t], j = nz[2 * t + 1];
  atomicOr(&excl[(size_t)i * 256 + (j >> 5)], 1u << (j & 31));
}

// ---------------------------------------------------------------------------
// 3) pass_a: fp32 cos GEMM.
//    R3 post-mortem: LDS-pipe-bound (104 b128/wave/chunk x ~12cyc, shared by
//    4 SIMDs -> VALUBusy 50%).  Fix: A operands come from wave-uniform loads
//    of repacked Ap (readfirstlane-forced uniform address + __restrict__ ->
//    s_load / SGPR operands; VMEM L1-hit fallback otherwise).  LDS now only
//    serves B: 32 cv + 8 staging b128 per wave per chunk (alpha=0.039,
//    LDS ~80% of VALU -> VALU-bound).
//    Accumulation: sequential-k fmaf (bitwise == numpy BLAS order).
// ---------------------------------------------------------------------------
__global__ __launch_bounds__(256, 3) void pass_a(const float* __restrict__ u,
                                                 const float* __restrict__ Ap,
                                                 const unsigned* __restrict__ excl,
                                                 int* __restrict__ rowjq,
                                                 float* __restrict__ rowvq,
                                                 int* __restrict__ row_cnt4) {
  __shared__ float colsB[32][260];   // [k][col]  1040 B stride (16B multiple)

  const int tid  = threadIdx.x;
  const int lane = tid & 63;
  const int wv   = tid >> 6;
  const int wv_u = __builtin_amdgcn_readfirstlane(wv);   // force uniform
  const int rblk = blockIdx.x >> 2;
  const int q    = blockIdx.x & 3;
  const int r0   = rblk * 32;
  const int jq0  = q * 2048;

  // A slices for this block: float4 index (k4g*32 + row), wave-uniform
  const float4* __restrict__ Arow =
      (const float4*)(Ap + (size_t)rblk * 32 * DIMS);

  float acc[8][4];
  int cnt[8];
#pragma unroll
  for (int rr = 0; rr < 8; ++rr) cnt[rr] = 0;

  const unsigned long long below = (1ull << lane) - 1ull;
  const int gi0 = r0 + wv * 8;

  // staging prefetch registers: pfr[s][c][t] = u[(jb+4l+c)*128 + kc+8w+4s+t]
  float pfr[2][4][4];
#define DO_PREFETCH(CS)                                                       \
  {                                                                           \
    int jb_ = jq0 + ((CS) >> 2) * 256;                                        \
    int kc_ = ((CS) & 3) * 32;                                                \
    _Pragma("unroll")                                                         \
    for (int s = 0; s < 2; ++s) {                                             \
      _Pragma("unroll")                                                       \
      for (int c = 0; c < 4; ++c) {                                           \
        float4 f = *(const float4*)(u + (size_t)(jb_ + 4 * lane + c) * DIMS + \
                                    kc_ + 8 * wv + 4 * s);                    \
        pfr[s][c][0] = f.x; pfr[s][c][1] = f.y;                               \
        pfr[s][c][2] = f.z; pfr[s][c][3] = f.w;                               \
      }                                                                       \
    }                                                                         \
  }

  DO_PREFETCH(0)

#pragma unroll 1
  for (int cs = 0; cs < 32; ++cs) {
    if ((cs & 3) == 0) {
#pragma unroll
      for (int rr = 0; rr < 8; ++rr)
#pragma unroll
        for (int cc = 0; cc < 4; ++cc) acc[rr][cc] = 0.f;
    }

    __syncthreads();   // previous chunk's colsB reads complete
    // wave w stages ks [8w, 8w+8): each instr writes a full contiguous
    // 1KB LDS row (conflict-free, measured 0 in R2/R3)
#pragma unroll
    for (int s = 0; s < 2; ++s)
#pragma unroll
      for (int t = 0; t < 4; ++t) {
        float4 v;
        v.x = pfr[s][0][t]; v.y = pfr[s][1][t];
        v.z = pfr[s][2][t]; v.w = pfr[s][3][t];
        *(float4*)&colsB[8 * wv + 4 * s + t][4 * lane] = v;
      }
    __syncthreads();

    if (cs + 1 < 32) DO_PREFETCH(cs + 1)   // hide L2 latency under compute

    const int k4base = (cs & 3) * 8;
    // compute: 8 k4-steps x (4 col b128 + 8 wave-uniform A loads + 128 FMA)
#pragma unroll
    for (int k4 = 0; k4 < 8; ++k4) {
      // wave-uniform A loads (scalarizable): 8 rows x 4 ks, contiguous 128 B
      float4 av[8];
#pragma unroll
      for (int rr = 0; rr < 8; ++rr)
        av[rr] = Arow[(size_t)(k4base + k4) * 32 + wv_u * 8 + rr];

      float cvf[4][4];
#pragma unroll
      for (int kk = 0; kk < 4; ++kk) {
        float4 f = *(const float4*)&colsB[k4 * 4 + kk][4 * lane];
        cvf[kk][0] = f.x; cvf[kk][1] = f.y; cvf[kk][2] = f.z; cvf[kk][3] = f.w;
      }
      // per-acc chain sees k ascending (kk outer) — bitwise == numpy
#pragma unroll
      for (int kk = 0; kk < 4; ++kk)
#pragma unroll
        for (int rr = 0; rr < 8; ++rr) {
          float a = (kk == 0) ? av[rr].x
                  : (kk == 1) ? av[rr].y
                  : (kk == 2) ? av[rr].z : av[rr].w;
#pragma unroll
          for (int cc = 0; cc < 4; ++cc)
            acc[rr][cc] = fmaf(a, cvf[kk][cc], acc[rr][cc]);
        }
    }

    // candidate scan after last chunk of each j-tile
    if ((cs & 3) == 3) {
      const int jb = jq0 + (cs >> 2) * 256;
      const int jcol0 = jb + lane * 4;
#pragma unroll
      for (int rr = 0; rr < 8; ++rr) {
        const int gi = gi0 + rr;
        unsigned word = excl[(size_t)gi * 256 + (jb >> 5) + (lane >> 3)];
        int bitbase = (lane & 7) * 4;
        bool pred[4];
        unsigned long long m[4];
#pragma unroll
        for (int cc = 0; cc < 4; ++cc) {
          float v = acc[rr][cc];
          pred[cc] = (v > COS_THR) && !((word >> (bitbase + cc)) & 1u) &&
                     (jcol0 + cc != gi);
          m[cc] = __ballot(pred[cc]);
        }
        int before = __popcll(m[0] & below) + __popcll(m[1] & below) +
                     __popcll(m[2] & below) + __popcll(m[3] & below);
        int base = cnt[rr] + before;
        int sub = 0;
        size_t cell = ((size_t)gi * 4 + q) * QCAP;
#pragma unroll
        for (int cc = 0; cc < 4; ++cc) {
          if (pred[cc]) {
            int idx = base + sub;
            if (idx < QCAP) {
              rowjq[cell + idx] = jcol0 + cc;
              rowvq[cell + idx] = acc[rr][cc];
            }
            ++sub;
          }
        }
        cnt[rr] += __popcll(m[0]) + __popcll(m[1]) +
                   __popcll(m[2]) + __popcll(m[3]);
      }
    }
  }

  if (lane == 0) {
#pragma unroll
    for (int rr = 0; rr < 8; ++rr)
      row_cnt4[(size_t)(gi0 + rr) * 4 + q] = min(cnt[rr], QCAP);
  }
#undef DO_PREFETCH
}

// ---------------------------------------------------------------------------
// 4) exclusive prefix scan over 32768 (row,quarter) counts — single block
// ---------------------------------------------------------------------------
__global__ __launch_bounds__(256) void scan_rows(const int* __restrict__ cnt,
                                                 int* __restrict__ off) {
  __shared__ int sm[256];
  int t = threadIdx.x;
  int base = t * 128;
  int s = 0;
  for (int i = 0; i < 128; ++i) s += cnt[base + i];
  sm[t] = s;
  __syncthreads();
  int x = s;
  for (int d = 1; d < 256; d <<= 1) {
    int y = (t >= d) ? sm[t - d] : 0;
    __syncthreads();
    x += y;
    sm[t] = x;
    __syncthreads();
  }
  int run = x - s;  // exclusive prefix
  for (int i = 0; i < 128; ++i) { off[base + i] = run; run += cnt[base + i]; }
  if (t == 255) off[NCELLS] = x;
}

// ---------------------------------------------------------------------------
// 5) compact per-cell buffers into the global candidate list
// ---------------------------------------------------------------------------
__global__ __launch_bounds__(256) void compact_rows(const int* __restrict__ cnt4,
                                                    const int* __restrict__ off,
                                                    const int* __restrict__ rowjq,
                                                    const float* __restrict__ rowvq,
                                                    int* __restrict__ cand_i,
                                                    int* __restrict__ cand_j,
                                                    float* __restrict__ cand_v) {
  int cell = blockIdx.x * 256 + threadIdx.x;
  if (cell >= NCELLS) return;
  int n = cnt4[cell], o0 = off[cell];
  int row = cell >> 2;
  for (int t = 0; t < n; ++t) {
    int o = o0 + t;
    if (o < KCAND) {
      cand_i[o] = row;
      cand_j[o] = rowjq[(size_t)cell * QCAP + t];
      cand_v[o] = rowvq[(size_t)cell * QCAP + t];
    }
  }
}

// 5b) pad the tail [M, K): nonzero fill_value=0, cand_val = cos[0,0] = -1
__global__ __launch_bounds__(256) void pad_cands(const int* __restrict__ off,
                                                 int* __restrict__ cand_i,
                                                 int* __restrict__ cand_j,
                                                 float* __restrict__ cand_v) {
  int t = blockIdx.x * 256 + threadIdx.x;
  if (t >= KCAND) return;
  int M = off[NCELLS];
  if (t >= M) { cand_i[t] = 0; cand_j[t] = 0; cand_v[t] = -1.0f; }
}

// ---------------------------------------------------------------------------
// 6) finalize — bit-exact (sequential fmaf chain matches BLAS order)
// ---------------------------------------------------------------------------
__global__ __launch_bounds__(256) void finalize_k(const float* __restrict__ ue,
                                                  const float* __restrict__ W,
                                                  const float* __restrict__ b,
                                                  const float* __restrict__ g,
                                                  const int* __restrict__ nz,
                                                  const int* __restrict__ cand_i,
                                                  const int* __restrict__ cand_j,
                                                  const float* __restrict__ cand_v,
                                                  float* __restrict__ out) {
  __shared__ float Ws[512];
  int tid = threadIdx.x;
  Ws[tid] = W[tid];
  Ws[tid + 256] = W[tid + 256];
  __syncthreads();

  int p = blockIdx.x * 256 + tid;
  if (p >= NTOT) return;

  int i, j;
  float wgt;
  if (p < EDGES) {
    i = nz[2 * p];
    j = nz[2 * p + 1];
    wgt = 1.0f;
  } else {
    int qq = p - EDGES;
    i = cand_i[qq];
    j = cand_j[qq];
    wgt = fmaxf(cand_v[qq], 0.0f);
  }

  const float4* ri = (const float4*)(ue + (size_t)i * DIMS);
  const float4* rj = (const float4*)(ue + (size_t)j * DIMS);
  float l0 = 0.f, l1 = 0.f;
#pragma unroll
  for (int kk = 0; kk < 32; ++kk) {
    float4 a = ri[kk];
    l0 = fmaf(a.x, Ws[kk * 4 + 0], l0);
    l0 = fmaf(a.y, Ws[kk * 4 + 1], l0);
    l0 = fmaf(a.z, Ws[kk * 4 + 2], l0);
    l0 = fmaf(a.w, Ws[kk * 4 + 3], l0);
    l1 = fmaf(a.x, Ws[256 + kk * 4 + 0], l1);
    l1 = fmaf(a.y, Ws[256 + kk * 4 + 1], l1);
    l1 = fmaf(a.z, Ws[256 + kk * 4 + 2], l1);
    l1 = fmaf(a.w, Ws[256 + kk * 4 + 3], l1);
  }
#pragma unroll
  for (int kk = 0; kk < 32; ++kk) {
    float4 a = rj[kk];
    l0 = fmaf(a.x, Ws[128 + kk * 4 + 0], l0);
    l0 = fmaf(a.y, Ws[128 + kk * 4 + 1], l0);
    l0 = fmaf(a.z, Ws[128 + kk * 4 + 2], l0);
    l0 = fmaf(a.w, Ws[128 + kk * 4 + 3], l0);
    l1 = fmaf(a.x, Ws[384 + kk * 4 + 0], l1);
    l1 = fmaf(a.y, Ws[384 + kk * 4 + 1], l1);
    l1 = fmaf(a.z, Ws[384 + kk * 4 + 2], l1);
    l1 = fmaf(a.w, Ws[384 + kk * 4 + 3], l1);
  }
  l0 += b[0];
  l1 += b[1];

  float s0 = l0 + g[2 * p];
  float s1 = l1 + g[2 * p + 1];
  float w = (s0 >= s1) ? wgt : 0.0f;

  out[p] = w;
  out[NTOT + p] = w;
  out[2 * NTOT + p] = w;
  out[3 * NTOT + 2 * p + 0] = (float)i;
  out[3 * NTOT + 2 * p + 1] = (float)j;
}

// ---------------------------------------------------------------------------
extern "C" void kernel_launch(void* const* d_in, const int* in_sizes, int n_in,
                              void* d_out, int out_size, void* d_ws, size_t ws_size,
                              hipStream_t stream) {
  (void)in_sizes; (void)n_in; (void)out_size; (void)ws_size;

  const float* user_emb = (const float*)d_in[0];
  const float* W        = (const float*)d_in[1];
  const float* b        = (const float*)d_in[2];
  const float* gnoise   = (const float*)d_in[3];
  const int*   nz       = (const int*)d_in[4];
  float* out = (float*)d_out;

  char* ws = (char*)d_ws;
  // ws layout (bytes)
  float*    u        = (float*)(ws + 0);                       //  4 MB
  float*    Ap       = (float*)(ws + (4u << 20));              //  4 MB repacked A
  unsigned* excl     = (unsigned*)(ws + (8u << 20));           //  8 MB
  int*      rowjq    = (int*)(ws + (16u << 20));               //  6 MB (32768*48*4)
  float*    rowvq    = (float*)(ws + (22u << 20));             //  6 MB
  int*      row_cnt4 = (int*)(ws + (28u << 20));               //  128 KB
  int*      row_off  = (int*)(ws + (28u << 20) + (256u << 10)); // 32769 ints
  int*      cand_i   = (int*)(ws + (29u << 20));               //  512 KB
  int*      cand_j   = (int*)(ws + (29u << 20) + (512u << 10));
  float*    cand_v   = (float*)(ws + (30u << 20));

  hipMemsetAsync(excl, 0, (size_t)N_USERS * 256 * sizeof(unsigned), stream);

  normalize_k<<<N_USERS / 256, 256, 0, stream>>>(user_emb, u);
  repack_A<<<N_USERS / 32, 256, 0, stream>>>(u, Ap);
  build_excl<<<EDGES / 256, 256, 0, stream>>>(nz, excl);
  pass_a<<<1024, 256, 0, stream>>>(u, Ap, excl, rowjq, rowvq, row_cnt4);
  scan_rows<<<1, 256, 0, stream>>>(row_cnt4, row_off);
  compact_rows<<<NCELLS / 256, 256, 0, stream>>>(row_cnt4, row_off, rowjq, rowvq,
                                                 cand_i, cand_j, cand_v);
  pad_cands<<<KCAND / 256, 256, 0, stream>>>(row_off, cand_i, cand_j, cand_v);
  finalize_k<<<NTOT / 256, 256, 0, stream>>>(user_emb, W, b, gnoise, nz,
                                             cand_i, cand_j, cand_v, out);
}

// Round 5
// 1016.727 us; speedup vs baseline: 1.1198x; 1.1198x over previous
//
#include <hip/hip_runtime.h>
#include <math.h>

#define N_USERS 8192
#define DIMS    128
#define EDGES   262144
#define KCAND   131072
#define NTOT    (EDGES + KCAND)      // 393216
#define QCAP    48                   // per-(row,quarter) candidate capacity
#define NCELLS  (N_USERS * 4)        // 32768 (row, quarter) cells
#define COS_THR 0.3f

// ---------------------------------------------------------------------------
// 1) normalize — bit-exact vs numpy (pairwise 8-acc + tree, double sqrt).
// ---------------------------------------------------------------------------
__global__ __launch_bounds__(256) void normalize_k(const float* __restrict__ x,
                                                   float* __restrict__ u) {
#pragma clang fp contract(off)
  int i = blockIdx.x * 256 + threadIdx.x;
  if (i >= N_USERS) return;
  const float* r = x + (size_t)i * DIMS;
  float a[8];
#pragma unroll
  for (int j = 0; j < 8; ++j) { float t = r[j]; a[j] = t * t; }
  for (int b8 = 8; b8 < DIMS; b8 += 8) {
#pragma unroll
    for (int j = 0; j < 8; ++j) { float t = r[b8 + j]; a[j] = a[j] + t * t; }
  }
  float s = ((a[0] + a[1]) + (a[2] + a[3])) + ((a[4] + a[5]) + (a[6] + a[7]));
  float n = (float)sqrt((double)s);
  n = fmaxf(n, 1e-12f);
  for (int k = 0; k < DIMS; ++k) u[(size_t)i * DIMS + k] = r[k] / n;
}

// ---------------------------------------------------------------------------
// 2) exclusion bitmask from nonzero_idx (8192 x 256 words)
// ---------------------------------------------------------------------------
__global__ __launch_bounds__(256) void build_excl(const int* __restrict__ nz,
                                                  unsigned* __restrict__ excl) {
  int t = blockIdx.x * 256 + threadIdx.x;
  if (t >= EDGES) return;
  int i = nz[2 * t], j = nz[2 * t + 1];
  atomicOr(&excl[(size_t)i * 256 + (j >> 5)], 1u << (j & 31));
}

// ---------------------------------------------------------------------------
// 3) pass_a: fp32 cos GEMM.
//    R3: LDS-pipe-bound (104 b128/wave/chunk; 64 were A-row broadcasts).
//    R4: A via VMEM loads -> compiler clustered loads -> scratch spill (2.9GB).
//    R5: A lives in per-lane REGISTERS for the whole kernel; operands are
//    broadcast with v_readlane (VALU->SGPR, the one scalar operand of
//    v_fma_f32).  Wave w owns rows 8w..8w+7, K=128: lane (row*8+kb) holds
//    float4 Av[s] = u[row][kb*16+4s ..+3].  Per k4-step: 32 readlane + 128
//    FMA; LDS only serves B (32 cv + 8 staging b128 per chunk).
//    No inner-loop VMEM, no launch_bounds cap => no spill.
//    Accumulation: sequential-k fmaf (bitwise == numpy BLAS order).
// ---------------------------------------------------------------------------
__global__ __launch_bounds__(256) void pass_a(const float* __restrict__ u,
                                              const unsigned* __restrict__ excl,
                                              int* __restrict__ rowjq,
                                              float* __restrict__ rowvq,
                                              int* __restrict__ row_cnt4) {
  __shared__ float colsB[32][260];   // [k][col]  1040 B stride (16B multiple)

  const int tid  = threadIdx.x;
  const int lane = tid & 63;
  const int wv   = tid >> 6;
  const int rblk = blockIdx.x >> 2;
  const int q    = blockIdx.x & 3;
  const int r0   = rblk * 32;
  const int jq0  = q * 2048;
  const int gi0  = r0 + wv * 8;

  // A in registers: lane (row*8+kb) holds u[gi0+row][kb*16+4s..+3], s=0..3
  float4 Av[4];
  {
    int row = lane >> 3, kb = lane & 7;
    const float* base = u + (size_t)(gi0 + row) * DIMS + kb * 16;
#pragma unroll
    for (int s = 0; s < 4; ++s) Av[s] = *(const float4*)(base + 4 * s);
  }

  float acc[8][4];
  int cnt[8];
#pragma unroll
  for (int rr = 0; rr < 8; ++rr) cnt[rr] = 0;

  const unsigned long long below = (1ull << lane) - 1ull;

  // staging prefetch registers: pfr[s][c][t] = u[(jb+4l+c)*128 + kc+8w+4s+t]
  float pfr[2][4][4];
#define DO_PREFETCH(CS)                                                       \
  {                                                                           \
    int jb_ = jq0 + ((CS) >> 2) * 256;                                        \
    int kc_ = ((CS) & 3) * 32;                                                \
    _Pragma("unroll")                                                         \
    for (int s = 0; s < 2; ++s) {                                             \
      _Pragma("unroll")                                                       \
      for (int c = 0; c < 4; ++c) {                                           \
        float4 f = *(const float4*)(u + (size_t)(jb_ + 4 * lane + c) * DIMS + \
                                    kc_ + 8 * wv + 4 * s);                    \
        pfr[s][c][0] = f.x; pfr[s][c][1] = f.y;                               \
        pfr[s][c][2] = f.z; pfr[s][c][3] = f.w;                               \
      }                                                                       \
    }                                                                         \
  }

  DO_PREFETCH(0)

#pragma unroll 1
  for (int cs = 0; cs < 32; ++cs) {
    if ((cs & 3) == 0) {
#pragma unroll
      for (int rr = 0; rr < 8; ++rr)
#pragma unroll
        for (int cc = 0; cc < 4; ++cc) acc[rr][cc] = 0.f;
    }

    __syncthreads();   // previous chunk's colsB reads complete
    // wave w stages ks [8w, 8w+8): contiguous 1KB rows (conflict-free)
#pragma unroll
    for (int s = 0; s < 2; ++s)
#pragma unroll
      for (int t = 0; t < 4; ++t) {
        float4 v;
        v.x = pfr[s][0][t]; v.y = pfr[s][1][t];
        v.z = pfr[s][2][t]; v.w = pfr[s][3][t];
        *(float4*)&colsB[8 * wv + 4 * s + t][4 * lane] = v;
      }
    __syncthreads();

    if (cs + 1 < 32) DO_PREFETCH(cs + 1)   // hide L2 latency under compute

    const int kb_base = (cs & 3) * 2;      // uniform (SGPR) — legal readlane idx
    // compute: 8 k4-steps x (4 col b128 + 32 readlane + 128 FMA)
#pragma unroll
    for (int k4 = 0; k4 < 8; ++k4) {
      const int kb = kb_base + (k4 >> 2);  // uniform
      const int s  = k4 & 3;               // compile-time after unroll

      float cvf[4][4];
#pragma unroll
      for (int kk = 0; kk < 4; ++kk) {
        float4 f = *(const float4*)&colsB[k4 * 4 + kk][4 * lane];
        cvf[kk][0] = f.x; cvf[kk][1] = f.y; cvf[kk][2] = f.z; cvf[kk][3] = f.w;
      }
      // per-acc chain sees k ascending (kk outer) — bitwise == numpy
#pragma unroll
      for (int kk = 0; kk < 4; ++kk) {
        float src = (kk == 0) ? Av[s].x
                  : (kk == 1) ? Av[s].y
                  : (kk == 2) ? Av[s].z : Av[s].w;
        int srcb = __float_as_int(src);
#pragma unroll
        for (int rr = 0; rr < 8; ++rr) {
          float a = __int_as_float(
              __builtin_amdgcn_readlane(srcb, rr * 8 + kb));
#pragma unroll
          for (int cc = 0; cc < 4; ++cc)
            acc[rr][cc] = fmaf(a, cvf[kk][cc], acc[rr][cc]);
        }
      }
    }

    // candidate scan after last chunk of each j-tile
    if ((cs & 3) == 3) {
      const int jb = jq0 + (cs >> 2) * 256;
      const int jcol0 = jb + lane * 4;
#pragma unroll
      for (int rr = 0; rr < 8; ++rr) {
        const int gi = gi0 + rr;
        unsigned word = excl[(size_t)gi * 256 + (jb >> 5) + (lane >> 3)];
        int bitbase = (lane & 7) * 4;
        bool pred[4];
        unsigned long long m[4];
#pragma unroll
        for (int cc = 0; cc < 4; ++cc) {
          float v = acc[rr][cc];
          pred[cc] = (v > COS_THR) && !((word >> (bitbase + cc)) & 1u) &&
                     (jcol0 + cc != gi);
          m[cc] = __ballot(pred[cc]);
        }
        int before = __popcll(m[0] & below) + __popcll(m[1] & below) +
                     __popcll(m[2] & below) + __popcll(m[3] & below);
        int base = cnt[rr] + before;
        int sub = 0;
        size_t cell = ((size_t)gi * 4 + q) * QCAP;
#pragma unroll
        for (int cc = 0; cc < 4; ++cc) {
          if (pred[cc]) {
            int idx = base + sub;
            if (idx < QCAP) {
              rowjq[cell + idx] = jcol0 + cc;
              rowvq[cell + idx] = acc[rr][cc];
            }
            ++sub;
          }
        }
        cnt[rr] += __popcll(m[0]) + __popcll(m[1]) +
                   __popcll(m[2]) + __popcll(m[3]);
      }
    }
  }

  if (lane == 0) {
#pragma unroll
    for (int rr = 0; rr < 8; ++rr)
      row_cnt4[(size_t)(gi0 + rr) * 4 + q] = min(cnt[rr], QCAP);
  }
#undef DO_PREFETCH
}

// ---------------------------------------------------------------------------
// 4) exclusive prefix scan over 32768 (row,quarter) counts — single block
// ---------------------------------------------------------------------------
__global__ __launch_bounds__(256) void scan_rows(const int* __restrict__ cnt,
                                                 int* __restrict__ off) {
  __shared__ int sm[256];
  int t = threadIdx.x;
  int base = t * 128;
  int s = 0;
  for (int i = 0; i < 128; ++i) s += cnt[base + i];
  sm[t] = s;
  __syncthreads();
  int x = s;
  for (int d = 1; d < 256; d <<= 1) {
    int y = (t >= d) ? sm[t - d] : 0;
    __syncthreads();
    x += y;
    sm[t] = x;
    __syncthreads();
  }
  int run = x - s;  // exclusive prefix
  for (int i = 0; i < 128; ++i) { off[base + i] = run; run += cnt[base + i]; }
  if (t == 255) off[NCELLS] = x;
}

// ---------------------------------------------------------------------------
// 5) compact per-cell buffers into the global candidate list
// ---------------------------------------------------------------------------
__global__ __launch_bounds__(256) void compact_rows(const int* __restrict__ cnt4,
                                                    const int* __restrict__ off,
                                                    const int* __restrict__ rowjq,
                                                    const float* __restrict__ rowvq,
                                                    int* __restrict__ cand_i,
                                                    int* __restrict__ cand_j,
                                                    float* __restrict__ cand_v) {
  int cell = blockIdx.x * 256 + threadIdx.x;
  if (cell >= NCELLS) return;
  int n = cnt4[cell], o0 = off[cell];
  int row = cell >> 2;
  for (int t = 0; t < n; ++t) {
    int o = o0 + t;
    if (o < KCAND) {
      cand_i[o] = row;
      cand_j[o] = rowjq[(size_t)cell * QCAP + t];
      cand_v[o] = rowvq[(size_t)cell * QCAP + t];
    }
  }
}

// 5b) pad the tail [M, K): nonzero fill_value=0, cand_val = cos[0,0] = -1
__global__ __launch_bounds__(256) void pad_cands(const int* __restrict__ off,
                                                 int* __restrict__ cand_i,
                                                 int* __restrict__ cand_j,
                                                 float* __restrict__ cand_v) {
  int t = blockIdx.x * 256 + threadIdx.x;
  if (t >= KCAND) return;
  int M = off[NCELLS];
  if (t >= M) { cand_i[t] = 0; cand_j[t] = 0; cand_v[t] = -1.0f; }
}

// ---------------------------------------------------------------------------
// 6) finalize — bit-exact (sequential fmaf chain matches BLAS order)
// ---------------------------------------------------------------------------
__global__ __launch_bounds__(256) void finalize_k(const float* __restrict__ ue,
                                                  const float* __restrict__ W,
                                                  const float* __restrict__ b,
                                                  const float* __restrict__ g,
                                                  const int* __restrict__ nz,
                                                  const int* __restrict__ cand_i,
                                                  const int* __restrict__ cand_j,
                                                  const float* __restrict__ cand_v,
                                                  float* __restrict__ out) {
  __shared__ float Ws[512];
  int tid = threadIdx.x;
  Ws[tid] = W[tid];
  Ws[tid + 256] = W[tid + 256];
  __syncthreads();

  int p = blockIdx.x * 256 + tid;
  if (p >= NTOT) return;

  int i, j;
  float wgt;
  if (p < EDGES) {
    i = nz[2 * p];
    j = nz[2 * p + 1];
    wgt = 1.0f;
  } else {
    int qq = p - EDGES;
    i = cand_i[qq];
    j = cand_j[qq];
    wgt = fmaxf(cand_v[qq], 0.0f);
  }

  const float4* ri = (const float4*)(ue + (size_t)i * DIMS);
  const float4* rj = (const float4*)(ue + (size_t)j * DIMS);
  float l0 = 0.f, l1 = 0.f;
#pragma unroll
  for (int kk = 0; kk < 32; ++kk) {
    float4 a = ri[kk];
    l0 = fmaf(a.x, Ws[kk * 4 + 0], l0);
    l0 = fmaf(a.y, Ws[kk * 4 + 1], l0);
    l0 = fmaf(a.z, Ws[kk * 4 + 2], l0);
    l0 = fmaf(a.w, Ws[kk * 4 + 3], l0);
    l1 = fmaf(a.x, Ws[256 + kk * 4 + 0], l1);
    l1 = fmaf(a.y, Ws[256 + kk * 4 + 1], l1);
    l1 = fmaf(a.z, Ws[256 + kk * 4 + 2], l1);
    l1 = fmaf(a.w, Ws[256 + kk * 4 + 3], l1);
  }
#pragma unroll
  for (int kk = 0; kk < 32; ++kk) {
    float4 a = rj[kk];
    l0 = fmaf(a.x, Ws[128 + kk * 4 + 0], l0);
    l0 = fmaf(a.y, Ws[128 + kk * 4 + 1], l0);
    l0 = fmaf(a.z, Ws[128 + kk * 4 + 2], l0);
    l0 = fmaf(a.w, Ws[128 + kk * 4 + 3], l0);
    l1 = fmaf(a.x, Ws[384 + kk * 4 + 0], l1);
    l1 = fmaf(a.y, Ws[384 + kk * 4 + 1], l1);
    l1 = fmaf(a.z, Ws[384 + kk * 4 + 2], l1);
    l1 = fmaf(a.w, Ws[384 + kk * 4 + 3], l1);
  }
  l0 += b[0];
  l1 += b[1];

  float s0 = l0 + g[2 * p];
  float s1 = l1 + g[2 * p + 1];
  float w = (s0 >= s1) ? wgt : 0.0f;

  out[p] = w;
  out[NTOT + p] = w;
  out[2 * NTOT + p] = w;
  out[3 * NTOT + 2 * p + 0] = (float)i;
  out[3 * NTOT + 2 * p + 1] = (float)j;
}

// ---------------------------------------------------------------------------
extern "C" void kernel_launch(void* const* d_in, const int* in_sizes, int n_in,
                              void* d_out, int out_size, void* d_ws, size_t ws_size,
                              hipStream_t stream) {
  (void)in_sizes; (void)n_in; (void)out_size; (void)ws_size;

  const float* user_emb = (const float*)d_in[0];
  const float* W        = (const float*)d_in[1];
  const float* b        = (const float*)d_in[2];
  const float* gnoise   = (const float*)d_in[3];
  const int*   nz       = (const int*)d_in[4];
  float* out = (float*)d_out;

  char* ws = (char*)d_ws;
  // ws layout (bytes)
  float*    u        = (float*)(ws + 0);                       //  4 MB
  unsigned* excl     = (unsigned*)(ws + (4u << 20));           //  8 MB
  int*      rowjq    = (int*)(ws + (12u << 20));               //  6 MB (32768*48*4)
  float*    rowvq    = (float*)(ws + (18u << 20));             //  6 MB
  int*      row_cnt4 = (int*)(ws + (24u << 20));               //  128 KB
  int*      row_off  = (int*)(ws + (24u << 20) + (256u << 10)); // 32769 ints
  int*      cand_i   = (int*)(ws + (25u << 20));               //  512 KB
  int*      cand_j   = (int*)(ws + (25u << 20) + (512u << 10));
  float*    cand_v   = (float*)(ws + (26u << 20));

  hipMemsetAsync(excl, 0, (size_t)N_USERS * 256 * sizeof(unsigned), stream);

  normalize_k<<<N_USERS / 256, 256, 0, stream>>>(user_emb, u);
  build_excl<<<EDGES / 256, 256, 0, stream>>>(nz, excl);
  pass_a<<<1024, 256, 0, stream>>>(u, excl, rowjq, rowvq, row_cnt4);
  scan_rows<<<1, 256, 0, stream>>>(row_cnt4, row_off);
  compact_rows<<<NCELLS / 256, 256, 0, stream>>>(row_cnt4, row_off, rowjq, rowvq,
                                                 cand_i, cand_j, cand_v);
  pad_cands<<<KCAND / 256, 256, 0, stream>>>(row_off, cand_i, cand_j, cand_v);
  finalize_k<<<NTOT / 256, 256, 0, stream>>>(user_emb, W, b, gnoise, nz,
                                             cand_i, cand_j, cand_v, out);
}

// Round 6
// 443.658 us; speedup vs baseline: 2.5662x; 2.2917x over previous
//
#include <hip/hip_runtime.h>
#include <hip/hip_bf16.h>
#include <math.h>

#define N_USERS 8192
#define DIMS    128
#define EDGES   262144
#define KCAND   131072
#define NTOT    (EDGES + KCAND)      // 393216
#define LISTCAP 131072
#define COS_THR 0.3f
#define EPS_SEL 6e-3f                // > hard error bound 4e-3 of bf16 cos
#define LOGIT_MARGIN 2e-3f           // > split-vs-chain rounding ~3e-5

typedef short bf16x8 __attribute__((ext_vector_type(8)));
typedef float f32x4  __attribute__((ext_vector_type(4)));

// ---------------------------------------------------------------------------
// 1) normalize (bit-exact vs numpy: pairwise 8-acc + tree + double sqrt)
//    + emit bf16 copy of normalized rows for MFMA.
// ---------------------------------------------------------------------------
__global__ __launch_bounds__(256) void normalize_k(const float* __restrict__ x,
                                                   float* __restrict__ un,
                                                   unsigned short* __restrict__ u0) {
#pragma clang fp contract(off)
  int i = blockIdx.x * 256 + threadIdx.x;
  if (i >= N_USERS) return;
  const float* r = x + (size_t)i * DIMS;
  float a[8];
#pragma unroll
  for (int j = 0; j < 8; ++j) { float t = r[j]; a[j] = t * t; }
  for (int b8 = 8; b8 < DIMS; b8 += 8) {
#pragma unroll
    for (int j = 0; j < 8; ++j) { float t = r[b8 + j]; a[j] = a[j] + t * t; }
  }
  float s = ((a[0] + a[1]) + (a[2] + a[3])) + ((a[4] + a[5]) + (a[6] + a[7]));
  float n = (float)sqrt((double)s);
  n = fmaxf(n, 1e-12f);
  for (int k = 0; k < DIMS; ++k) {
    float t = r[k] / n;
    un[(size_t)i * DIMS + k] = t;
    __hip_bfloat16 h = __float2bfloat16(t);   // RNE
    u0[(size_t)i * DIMS + k] = *(unsigned short*)&h;
  }
}

// ---------------------------------------------------------------------------
// 2) exclusion bitmask from nonzero_idx (8192 x 256 words)
// ---------------------------------------------------------------------------
__global__ __launch_bounds__(256) void build_excl(const int* __restrict__ nz,
                                                  unsigned* __restrict__ excl) {
  int t = blockIdx.x * 256 + threadIdx.x;
  if (t >= EDGES) return;
  int i = nz[2 * t], j = nz[2 * t + 1];
  atomicOr(&excl[(size_t)i * 256 + (j >> 5)], 1u << (j & 31));
}

// ---------------------------------------------------------------------------
// 3) mfma_pass: S = U0·U0^T (bf16 MFMA, fp32 acc), fused threshold epilogue.
//    Block tile 128x128 (grid 64x64), 4 waves, wave tile 64x64 = 4x4 of
//    16x16x32 MFMA tiles (acc 64 VGPR).  K staged per 32-chunk into LDS
//    layout As/Bs[quad][row][8 bf16] so a/b fragment reads are contiguous
//    ds_read_b128 (A[m=lane&15][k=quad*8+j]; B^T row-major == same pattern;
//    C: col(n)=lane&15, row(m)=quad*4+reg — m89/m92-verified layouts).
//    Epilogue: v > THR-EPS -> append (i,j,v,border_flag) to unordered list;
//    |v-THR|<=EPS entries are provisional, resolved exactly later.
// ---------------------------------------------------------------------------
__global__ __launch_bounds__(256) void mfma_pass(const unsigned short* __restrict__ u0,
                                                 const unsigned* __restrict__ excl,
                                                 int* __restrict__ list_i,
                                                 int* __restrict__ list_j,
                                                 float* __restrict__ list_v,
                                                 int* __restrict__ list_f,
                                                 int* __restrict__ gcount) {
  __shared__ __align__(16) unsigned short As[4][128][8];  // 8 KB
  __shared__ __align__(16) unsigned short Bs[4][128][8];  // 8 KB

  const int tid  = threadIdx.x;
  const int lane = tid & 63;
  const int wv   = tid >> 6;
  const int quad = lane >> 4;
  const int l15  = lane & 15;
  const int bI   = blockIdx.x & 63;
  const int bJ   = blockIdx.x >> 6;
  const int I0   = bI * 128, J0 = bJ * 128;
  const int moff = (wv & 1) * 64, noff = (wv >> 1) * 64;

  f32x4 acc[4][4];
#pragma unroll
  for (int mt = 0; mt < 4; ++mt)
#pragma unroll
    for (int nt = 0; nt < 4; ++nt)
#pragma unroll
      for (int g = 0; g < 4; ++g) acc[mt][nt][g] = 0.f;

  // prefetch regs: staging element d = it*256+tid -> (quad=d>>7, row=d&127)
  uint4 pA[2], pB[2];
#define PF(KC)                                                                \
  {                                                                           \
    _Pragma("unroll")                                                         \
    for (int it = 0; it < 2; ++it) {                                          \
      int d = it * 256 + tid;                                                 \
      int row = d & 127, qd = d >> 7;                                         \
      pA[it] = *(const uint4*)((const char*)u0 +                              \
                (size_t)(I0 + row) * 256 + (KC) * 64 + qd * 16);              \
      pB[it] = *(const uint4*)((const char*)u0 +                              \
                (size_t)(J0 + row) * 256 + (KC) * 64 + qd * 16);              \
    }                                                                         \
  }

  PF(0)

#pragma unroll 1
  for (int kc = 0; kc < 4; ++kc) {
    __syncthreads();
#pragma unroll
    for (int it = 0; it < 2; ++it) {
      ((uint4*)As)[it * 256 + tid] = pA[it];
      ((uint4*)Bs)[it * 256 + tid] = pB[it];
    }
    __syncthreads();
    if (kc < 3) PF(kc + 1)

    bf16x8 af[4], bf[4];
#pragma unroll
    for (int mt = 0; mt < 4; ++mt)
      af[mt] = *(const bf16x8*)&As[quad][moff + mt * 16 + l15][0];
#pragma unroll
    for (int nt = 0; nt < 4; ++nt)
      bf[nt] = *(const bf16x8*)&Bs[quad][noff + nt * 16 + l15][0];
#pragma unroll
    for (int mt = 0; mt < 4; ++mt)
#pragma unroll
      for (int nt = 0; nt < 4; ++nt)
        acc[mt][nt] = __builtin_amdgcn_mfma_f32_16x16x32_bf16(
            af[mt], bf[nt], acc[mt][nt], 0, 0, 0);
  }
#undef PF

  // epilogue: threshold scan with borderline window
#pragma unroll
  for (int mt = 0; mt < 4; ++mt)
#pragma unroll
    for (int nt = 0; nt < 4; ++nt)
#pragma unroll
      for (int g = 0; g < 4; ++g) {
        float v = acc[mt][nt][g];
        if (v > COS_THR - EPS_SEL) {
          int i = I0 + moff + mt * 16 + quad * 4 + g;
          int j = J0 + noff + nt * 16 + l15;
          unsigned word = excl[(size_t)i * 256 + (j >> 5)];
          if (!((word >> (j & 31)) & 1u) && i != j) {
            int flag = (v <= COS_THR + EPS_SEL) ? 1 : 0;
            int idx = atomicAdd(gcount, 1);
            if (idx < LISTCAP) {
              list_i[idx] = i; list_j[idx] = j;
              list_v[idx] = v; list_f[idx] = flag;
            }
          }
        }
      }
}

// ---------------------------------------------------------------------------
// 4) resolve borderline entries with the exact sequential-fmaf chain
//    (empirically bitwise == numpy's cos — R1/R3 evidence)
// ---------------------------------------------------------------------------
__global__ __launch_bounds__(256) void resolve_k(const float* __restrict__ un,
                                                 int* __restrict__ list_i,
                                                 const int* __restrict__ list_j,
                                                 float* __restrict__ list_v,
                                                 int* __restrict__ list_f,
                                                 const int* __restrict__ gcount) {
  int t = blockIdx.x * 256 + threadIdx.x;
  int n = min(*gcount, LISTCAP);
  if (t >= n || !list_f[t]) return;
  int i = list_i[t], j = list_j[t];
  const float* a = un + (size_t)i * DIMS;
  const float* b = un + (size_t)j * DIMS;
  float s = 0.f;
  for (int k = 0; k < DIMS; ++k) s = fmaf(a[k], b[k], s);
  if (s > COS_THR) { list_v[t] = s; }
  else             { list_i[t] = -1; }   // dead
}

// 5) histogram per row
__global__ __launch_bounds__(256) void hist_k(const int* __restrict__ list_i,
                                              const int* __restrict__ gcount,
                                              int* __restrict__ row_cnt) {
  int t = blockIdx.x * 256 + threadIdx.x;
  int n = min(*gcount, LISTCAP);
  if (t >= n) return;
  int i = list_i[t];
  if (i >= 0) atomicAdd(&row_cnt[i], 1);
}

// 6) exclusive scan over 8192 row counts (single block)
__global__ __launch_bounds__(256) void scan8k(const int* __restrict__ cnt,
                                              int* __restrict__ off) {
  __shared__ int sm[256];
  int t = threadIdx.x;
  int base = t * 32;
  int s = 0;
  for (int i = 0; i < 32; ++i) s += cnt[base + i];
  sm[t] = s;
  __syncthreads();
  int x = s;
  for (int d = 1; d < 256; d <<= 1) {
    int y = (t >= d) ? sm[t - d] : 0;
    __syncthreads();
    x += y;
    sm[t] = x;
    __syncthreads();
  }
  int run = x - s;
  for (int i = 0; i < 32; ++i) { off[base + i] = run; run += cnt[base + i]; }
  if (t == 255) off[N_USERS] = x;
}

// 7) scatter live entries to per-row spans (unsorted within row)
__global__ __launch_bounds__(256) void scatter_k(const int* __restrict__ list_i,
                                                 const int* __restrict__ list_j,
                                                 const float* __restrict__ list_v,
                                                 const int* __restrict__ gcount,
                                                 const int* __restrict__ row_off,
                                                 int* __restrict__ row_pos,
                                                 int* __restrict__ cand_i,
                                                 int* __restrict__ cand_j,
                                                 float* __restrict__ cand_v) {
  int t = blockIdx.x * 256 + threadIdx.x;
  int n = min(*gcount, LISTCAP);
  if (t >= n) return;
  int i = list_i[t];
  if (i < 0) return;
  int pos = row_off[i] + atomicAdd(&row_pos[i], 1);
  if (pos < KCAND) {
    cand_i[pos] = i;
    cand_j[pos] = list_j[t];
    cand_v[pos] = list_v[t];
  }
}

// 8) sort each row's span ascending by j (row degree ~Poisson(2.4))
__global__ __launch_bounds__(256) void sortrow_k(const int* __restrict__ row_off,
                                                 const int* __restrict__ row_cnt,
                                                 int* __restrict__ cand_j,
                                                 float* __restrict__ cand_v) {
  int r = blockIdx.x * 256 + threadIdx.x;
  if (r >= N_USERS) return;
  int o = row_off[r], c = row_cnt[r];
  if (o + c > KCAND) c = max(0, KCAND - o);
  for (int a = 1; a < c; ++a) {
    int jv = cand_j[o + a];
    float vv = cand_v[o + a];
    int b = a - 1;
    while (b >= 0 && cand_j[o + b] > jv) {
      cand_j[o + b + 1] = cand_j[o + b];
      cand_v[o + b + 1] = cand_v[o + b];
      --b;
    }
    cand_j[o + b + 1] = jv;
    cand_v[o + b + 1] = vv;
  }
}

// 9) pad tail [M, K): nonzero fill_value=0 -> pair (0,0), cos[0,0] = -1
__global__ __launch_bounds__(256) void pad_k(const int* __restrict__ row_off,
                                             int* __restrict__ cand_i,
                                             int* __restrict__ cand_j,
                                             float* __restrict__ cand_v) {
  int t = blockIdx.x * 256 + threadIdx.x;
  if (t >= KCAND) return;
  int M = row_off[N_USERS];
  if (t >= M) { cand_i[t] = 0; cand_j[t] = 0; cand_v[t] = -1.0f; }
}

// ---------------------------------------------------------------------------
// 10) per-user partial logits: P[i] = {W0·ue_i, W0'·ue_i, W1·ue_i, W1'·ue_i}
//     (W' = second 128 cols).  Sequential fmaf chains.
// ---------------------------------------------------------------------------
__global__ __launch_bounds__(256) void wprep_k(const float* __restrict__ ue,
                                               const float* __restrict__ W,
                                               float4* __restrict__ P) {
  int i = blockIdx.x * 256 + threadIdx.x;
  if (i >= N_USERS) return;
  const float* r = ue + (size_t)i * DIMS;
  float a0 = 0.f, b0 = 0.f, a1 = 0.f, b1 = 0.f;
  for (int k = 0; k < DIMS; ++k) {
    float t = r[k];
    a0 = fmaf(t, W[k], a0);
    b0 = fmaf(t, W[128 + k], b0);
    a1 = fmaf(t, W[256 + k], a1);
    b1 = fmaf(t, W[384 + k], b1);
  }
  P[i] = make_float4(a0, b0, a1, b1);
}

// ---------------------------------------------------------------------------
// 11) finalize: split logits via P (+ exact-chain fallback near ties),
//     gumbel argmax, weights, outputs.
// ---------------------------------------------------------------------------
__global__ __launch_bounds__(256) void finalize_k(const float* __restrict__ ue,
                                                  const float* __restrict__ W,
                                                  const float* __restrict__ b,
                                                  const float* __restrict__ g,
                                                  const int* __restrict__ nz,
                                                  const int* __restrict__ cand_i,
                                                  const int* __restrict__ cand_j,
                                                  const float* __restrict__ cand_v,
                                                  const float4* __restrict__ P,
                                                  float* __restrict__ out) {
  int p = blockIdx.x * 256 + threadIdx.x;
  if (p >= NTOT) return;

  int i, j;
  float wgt;
  if (p < EDGES) {
    i = nz[2 * p];
    j = nz[2 * p + 1];
    wgt = 1.0f;
  } else {
    int q = p - EDGES;
    i = cand_i[q];
    j = cand_j[q];
    wgt = fmaxf(cand_v[q], 0.0f);
  }

  float4 Pi = P[i], Pj = P[j];
  float l0 = Pi.x + Pj.y + b[0];
  float l1 = Pi.z + Pj.w + b[1];
  float g0 = g[2 * p], g1 = g[2 * p + 1];
  float s0 = l0 + g0, s1 = l1 + g1;

  if (fabsf(s0 - s1) < LOGIT_MARGIN) {
    // exact sequential chain (bitwise == numpy — R1 verified)
    const float* ri = ue + (size_t)i * DIMS;
    const float* rj = ue + (size_t)j * DIMS;
    float e0 = 0.f, e1 = 0.f;
    for (int k = 0; k < DIMS; ++k) {
      e0 = fmaf(ri[k], W[k], e0);
      e1 = fmaf(ri[k], W[256 + k], e1);
    }
    for (int k = 0; k < DIMS; ++k) {
      e0 = fmaf(rj[k], W[128 + k], e0);
      e1 = fmaf(rj[k], W[384 + k], e1);
    }
    s0 = (e0 + b[0]) + g0;
    s1 = (e1 + b[1]) + g1;
  }

  float w = (s0 >= s1) ? wgt : 0.0f;

  out[p] = w;
  out[NTOT + p] = w;
  out[2 * NTOT + p] = w;
  out[3 * NTOT + 2 * p + 0] = (float)i;
  out[3 * NTOT + 2 * p + 1] = (float)j;
}

// ---------------------------------------------------------------------------
extern "C" void kernel_launch(void* const* d_in, const int* in_sizes, int n_in,
                              void* d_out, int out_size, void* d_ws, size_t ws_size,
                              hipStream_t stream) {
  (void)in_sizes; (void)n_in; (void)out_size; (void)ws_size;

  const float* user_emb = (const float*)d_in[0];
  const float* W        = (const float*)d_in[1];
  const float* b        = (const float*)d_in[2];
  const float* gnoise   = (const float*)d_in[3];
  const int*   nz       = (const int*)d_in[4];
  float* out = (float*)d_out;

  char* ws = (char*)d_ws;
  float*          un      = (float*)(ws + 0);                        // 4 MB
  unsigned short* u0      = (unsigned short*)(ws + (4u << 20));      // 2 MB
  unsigned*       excl    = (unsigned*)(ws + (6u << 20));            // 8 MB
  int*            list_i  = (int*)(ws + (14u << 20));                // 512 KB
  int*            list_j  = (int*)(ws + (14u << 20) + (512u << 10)); // 512 KB
  float*          list_v  = (float*)(ws + (15u << 20));              // 512 KB
  int*            list_f  = (int*)(ws + (15u << 20) + (512u << 10)); // 512 KB
  int*            gcount  = (int*)(ws + (16u << 20));                // 4 B
  int*            row_cnt = (int*)(ws + (16u << 20) + (4u << 10));   // 32 KB
  int*            row_off = (int*)(ws + (16u << 20) + (40u << 10));  // 32.8 KB
  int*            row_pos = (int*)(ws + (16u << 20) + (80u << 10));  // 32 KB
  int*            cand_i  = (int*)(ws + (17u << 20));                // 512 KB
  int*            cand_j  = (int*)(ws + (17u << 20) + (512u << 10)); // 512 KB
  float*          cand_v  = (float*)(ws + (18u << 20));              // 512 KB
  float4*         P       = (float4*)(ws + (18u << 20) + (512u << 10)); // 128 KB

  hipMemsetAsync(excl, 0, (size_t)N_USERS * 256 * sizeof(unsigned), stream);
  hipMemsetAsync(gcount, 0, sizeof(int), stream);
  hipMemsetAsync(row_cnt, 0, (size_t)N_USERS * sizeof(int), stream);
  hipMemsetAsync(row_pos, 0, (size_t)N_USERS * sizeof(int), stream);

  normalize_k<<<N_USERS / 256, 256, 0, stream>>>(user_emb, un, u0);
  build_excl<<<EDGES / 256, 256, 0, stream>>>(nz, excl);
  wprep_k<<<N_USERS / 256, 256, 0, stream>>>(user_emb, W, P);
  mfma_pass<<<64 * 64, 256, 0, stream>>>(u0, excl, list_i, list_j, list_v,
                                         list_f, gcount);
  resolve_k<<<LISTCAP / 256, 256, 0, stream>>>(un, list_i, list_j, list_v,
                                               list_f, gcount);
  hist_k<<<LISTCAP / 256, 256, 0, stream>>>(list_i, gcount, row_cnt);
  scan8k<<<1, 256, 0, stream>>>(row_cnt, row_off);
  scatter_k<<<LISTCAP / 256, 256, 0, stream>>>(list_i, list_j, list_v, gcount,
                                               row_off, row_pos,
                                               cand_i, cand_j, cand_v);
  sortrow_k<<<N_USERS / 256, 256, 0, stream>>>(row_off, row_cnt, cand_j, cand_v);
  pad_k<<<KCAND / 256, 256, 0, stream>>>(row_off, cand_i, cand_j, cand_v);
  finalize_k<<<NTOT / 256, 256, 0, stream>>>(user_emb, W, b, gnoise, nz,
                                             cand_i, cand_j, cand_v, P, out);
}

// Round 7
// 211.027 us; speedup vs baseline: 5.3951x; 2.1024x over previous
//
#include <hip/hip_runtime.h>
#include <hip/hip_bf16.h>
#include <math.h>

#define N_USERS 8192
#define DIMS    128
#define EDGES   262144
#define KCAND   131072
#define NTOT    (EDGES + KCAND)      // 393216
#define LISTCAP 131072
#define CAPB    1024                 // per-block LDS staging capacity
#define COS_THR 0.3f
#define EPS_SEL 6e-3f                // > hard error bound ~4e-3 of bf16 cos
#define LOGIT_MARGIN 2e-3f
#define DEADKEY 0xFFFFFFFFu

typedef short bf16x8 __attribute__((ext_vector_type(8)));
typedef float f32x4  __attribute__((ext_vector_type(4)));

// ---------------------------------------------------------------------------
// 1) normalize (bit-exact vs numpy) + bf16 copy for MFMA
// ---------------------------------------------------------------------------
__global__ __launch_bounds__(256) void normalize_k(const float* __restrict__ x,
                                                   float* __restrict__ un,
                                                   unsigned short* __restrict__ u0) {
#pragma clang fp contract(off)
  int i = blockIdx.x * 256 + threadIdx.x;
  if (i >= N_USERS) return;
  const float* r = x + (size_t)i * DIMS;
  float a[8];
#pragma unroll
  for (int j = 0; j < 8; ++j) { float t = r[j]; a[j] = t * t; }
  for (int b8 = 8; b8 < DIMS; b8 += 8) {
#pragma unroll
    for (int j = 0; j < 8; ++j) { float t = r[b8 + j]; a[j] = a[j] + t * t; }
  }
  float s = ((a[0] + a[1]) + (a[2] + a[3])) + ((a[4] + a[5]) + (a[6] + a[7]));
  float n = (float)sqrt((double)s);
  n = fmaxf(n, 1e-12f);
  for (int k = 0; k < DIMS; ++k) {
    float t = r[k] / n;
    un[(size_t)i * DIMS + k] = t;
    __hip_bfloat16 h = __float2bfloat16(t);
    u0[(size_t)i * DIMS + k] = *(unsigned short*)&h;
  }
}

// ---------------------------------------------------------------------------
// 2) exclusion bitmask (8192 x 256 words)
// ---------------------------------------------------------------------------
__global__ __launch_bounds__(256) void build_excl(const int* __restrict__ nz,
                                                  unsigned* __restrict__ excl) {
  int t = blockIdx.x * 256 + threadIdx.x;
  if (t >= EDGES) return;
  int i = nz[2 * t], j = nz[2 * t + 1];
  atomicOr(&excl[(size_t)i * 256 + (j >> 5)], 1u << (j & 31));
}

// ---------------------------------------------------------------------------
// 3) mfma_pass: upper-triangular block sweep (bJ >= bI, 2080 blocks).
//    R6 post-mortem: 292us with all pipes idle — ~21K same-address
//    device-scope atomics from 64 divergent sites convoyed all waves
//    (41 MB WRITE = line ping-pong).  R7: epilogue appends to per-block
//    LDS staging (LDS atomics), ONE global atomicAdd per block at flush;
//    excl/diag filtering deferred to resolve_k.  Symmetric mirror-emit.
// ---------------------------------------------------------------------------
__global__ __launch_bounds__(256) void mfma_pass(const unsigned short* __restrict__ u0,
                                                 unsigned* __restrict__ list_key,
                                                 float* __restrict__ list_v,
                                                 int* __restrict__ gcount) {
  __shared__ __align__(16) unsigned short As[4][128][8];  // 8 KB
  __shared__ __align__(16) unsigned short Bs[4][128][8];  // 8 KB
  __shared__ unsigned skey[CAPB];                         // 4 KB
  __shared__ float    sval[CAPB];                         // 4 KB
  __shared__ int lcnt, lbase;

  const int tid  = threadIdx.x;
  const int lane = tid & 63;
  const int wv   = tid >> 6;
  const int quad = lane >> 4;
  const int l15  = lane & 15;

  // triangular decode: blocks enumerate (bI, bJ) with bJ >= bI
  int rem = blockIdx.x, bI = 0;
  while (rem >= 64 - bI) { rem -= 64 - bI; ++bI; }
  const int bJ = bI + rem;
  const int I0 = bI * 128, J0 = bJ * 128;
  const int moff = (wv & 1) * 64, noff = (wv >> 1) * 64;

  if (tid == 0) lcnt = 0;

  f32x4 acc[4][4];
#pragma unroll
  for (int mt = 0; mt < 4; ++mt)
#pragma unroll
    for (int nt = 0; nt < 4; ++nt)
#pragma unroll
      for (int g = 0; g < 4; ++g) acc[mt][nt][g] = 0.f;

  uint4 pA[2], pB[2];
#define PF(KC)                                                                \
  {                                                                           \
    _Pragma("unroll")                                                         \
    for (int it = 0; it < 2; ++it) {                                          \
      int d = it * 256 + tid;                                                 \
      int row = d & 127, qd = d >> 7;                                         \
      pA[it] = *(const uint4*)((const char*)u0 +                              \
                (size_t)(I0 + row) * 256 + (KC) * 64 + qd * 16);              \
      pB[it] = *(const uint4*)((const char*)u0 +                              \
                (size_t)(J0 + row) * 256 + (KC) * 64 + qd * 16);              \
    }                                                                         \
  }

  PF(0)

#pragma unroll 1
  for (int kc = 0; kc < 4; ++kc) {
    __syncthreads();
#pragma unroll
    for (int it = 0; it < 2; ++it) {
      ((uint4*)As)[it * 256 + tid] = pA[it];
      ((uint4*)Bs)[it * 256 + tid] = pB[it];
    }
    __syncthreads();
    if (kc < 3) PF(kc + 1)

    bf16x8 af[4], bfr[4];
#pragma unroll
    for (int mt = 0; mt < 4; ++mt)
      af[mt] = *(const bf16x8*)&As[quad][moff + mt * 16 + l15][0];
#pragma unroll
    for (int nt = 0; nt < 4; ++nt)
      bfr[nt] = *(const bf16x8*)&Bs[quad][noff + nt * 16 + l15][0];
#pragma unroll
    for (int mt = 0; mt < 4; ++mt)
#pragma unroll
      for (int nt = 0; nt < 4; ++nt)
        acc[mt][nt] = __builtin_amdgcn_mfma_f32_16x16x32_bf16(
            af[mt], bfr[nt], acc[mt][nt], 0, 0, 0);
  }
#undef PF

  // epilogue: compare + rare LDS append (no excl loads, no global atomics)
  const bool mirror = (bI != bJ);
#pragma unroll
  for (int mt = 0; mt < 4; ++mt)
#pragma unroll
    for (int nt = 0; nt < 4; ++nt)
#pragma unroll
      for (int g = 0; g < 4; ++g) {
        float v = acc[mt][nt][g];
        if (v > COS_THR - EPS_SEL) {
          int i = I0 + moff + mt * 16 + quad * 4 + g;
          int j = J0 + noff + nt * 16 + l15;
          int idx = atomicAdd(&lcnt, 1);
          if (idx < CAPB) { skey[idx] = ((unsigned)i << 13) | j; sval[idx] = v; }
          if (mirror) {
            int idx2 = atomicAdd(&lcnt, 1);
            if (idx2 < CAPB) { skey[idx2] = ((unsigned)j << 13) | i; sval[idx2] = v; }
          }
        }
      }

  __syncthreads();
  int n = min(lcnt, CAPB);
  if (tid == 0) lbase = atomicAdd(gcount, n);
  __syncthreads();
  int base = lbase;
  for (int t = tid; t < n; t += 256) {
    int o = base + t;
    if (o < LISTCAP) { list_key[o] = skey[t]; list_v[o] = sval[t]; }
  }
}

// ---------------------------------------------------------------------------
// 4) resolve: per-entry excl/diag filter; borderline entries get the exact
//    sequential-fmaf chain (bitwise == numpy) to decide + exact value.
// ---------------------------------------------------------------------------
__global__ __launch_bounds__(256) void resolve_k(const float* __restrict__ un,
                                                 const unsigned* __restrict__ excl,
                                                 unsigned* __restrict__ list_key,
                                                 float* __restrict__ list_v,
                                                 const int* __restrict__ gcount) {
  int t = blockIdx.x * 256 + threadIdx.x;
  int n = min(*gcount, LISTCAP);
  if (t >= n) return;
  unsigned key = list_key[t];
  int i = key >> 13, j = key & 8191;
  unsigned word = excl[(size_t)i * 256 + (j >> 5)];
  if (i == j || ((word >> (j & 31)) & 1u)) { list_key[t] = DEADKEY; return; }
  float v = list_v[t];
  if (v <= COS_THR + EPS_SEL) {   // borderline: decide exactly
    const float* a = un + (size_t)i * DIMS;
    const float* b = un + (size_t)j * DIMS;
    float s = 0.f;
    for (int k = 0; k < DIMS; ++k) s = fmaf(a[k], b[k], s);
    if (s > COS_THR) list_v[t] = s;
    else             list_key[t] = DEADKEY;
  }
}

// 5) histogram per row
__global__ __launch_bounds__(256) void hist_k(const unsigned* __restrict__ list_key,
                                              const int* __restrict__ gcount,
                                              int* __restrict__ row_cnt) {
  int t = blockIdx.x * 256 + threadIdx.x;
  int n = min(*gcount, LISTCAP);
  if (t >= n) return;
  unsigned key = list_key[t];
  if (key != DEADKEY) atomicAdd(&row_cnt[key >> 13], 1);
}

// 6) exclusive scan over 8192 row counts (single block)
__global__ __launch_bounds__(256) void scan8k(const int* __restrict__ cnt,
                                              int* __restrict__ off) {
  __shared__ int sm[256];
  int t = threadIdx.x;
  int base = t * 32;
  int s = 0;
  for (int i = 0; i < 32; ++i) s += cnt[base + i];
  sm[t] = s;
  __syncthreads();
  int x = s;
  for (int d = 1; d < 256; d <<= 1) {
    int y = (t >= d) ? sm[t - d] : 0;
    __syncthreads();
    x += y;
    sm[t] = x;
    __syncthreads();
  }
  int run = x - s;
  for (int i = 0; i < 32; ++i) { off[base + i] = run; run += cnt[base + i]; }
  if (t == 255) off[N_USERS] = x;
}

// 7) scatter live entries to per-row spans
__global__ __launch_bounds__(256) void scatter_k(const unsigned* __restrict__ list_key,
                                                 const float* __restrict__ list_v,
                                                 const int* __restrict__ gcount,
                                                 const int* __restrict__ row_off,
                                                 int* __restrict__ row_pos,
                                                 int* __restrict__ cand_i,
                                                 int* __restrict__ cand_j,
                                                 float* __restrict__ cand_v) {
  int t = blockIdx.x * 256 + threadIdx.x;
  int n = min(*gcount, LISTCAP);
  if (t >= n) return;
  unsigned key = list_key[t];
  if (key == DEADKEY) return;
  int i = key >> 13, j = key & 8191;
  int pos = row_off[i] + atomicAdd(&row_pos[i], 1);
  if (pos < KCAND) {
    cand_i[pos] = i;
    cand_j[pos] = j;
    cand_v[pos] = list_v[t];
  }
}

// 8) sort each row's span ascending by j
__global__ __launch_bounds__(256) void sortrow_k(const int* __restrict__ row_off,
                                                 const int* __restrict__ row_cnt,
                                                 int* __restrict__ cand_j,
                                                 float* __restrict__ cand_v) {
  int r = blockIdx.x * 256 + threadIdx.x;
  if (r >= N_USERS) return;
  int o = row_off[r], c = row_cnt[r];
  if (o + c > KCAND) c = max(0, KCAND - o);
  for (int a = 1; a < c; ++a) {
    int jv = cand_j[o + a];
    float vv = cand_v[o + a];
    int b = a - 1;
    while (b >= 0 && cand_j[o + b] > jv) {
      cand_j[o + b + 1] = cand_j[o + b];
      cand_v[o + b + 1] = cand_v[o + b];
      --b;
    }
    cand_j[o + b + 1] = jv;
    cand_v[o + b + 1] = vv;
  }
}

// 9) pad tail [M, K): pair (0,0), cos[0,0] = -1
__global__ __launch_bounds__(256) void pad_k(const int* __restrict__ row_off,
                                             int* __restrict__ cand_i,
                                             int* __restrict__ cand_j,
                                             float* __restrict__ cand_v) {
  int t = blockIdx.x * 256 + threadIdx.x;
  if (t >= KCAND) return;
  int M = row_off[N_USERS];
  if (t >= M) { cand_i[t] = 0; cand_j[t] = 0; cand_v[t] = -1.0f; }
}

// 10) per-user partial logits
__global__ __launch_bounds__(256) void wprep_k(const float* __restrict__ ue,
                                               const float* __restrict__ W,
                                               float4* __restrict__ P) {
  int i = blockIdx.x * 256 + threadIdx.x;
  if (i >= N_USERS) return;
  const float* r = ue + (size_t)i * DIMS;
  float a0 = 0.f, b0 = 0.f, a1 = 0.f, b1 = 0.f;
  for (int k = 0; k < DIMS; ++k) {
    float t = r[k];
    a0 = fmaf(t, W[k], a0);
    b0 = fmaf(t, W[128 + k], b0);
    a1 = fmaf(t, W[256 + k], a1);
    b1 = fmaf(t, W[384 + k], b1);
  }
  P[i] = make_float4(a0, b0, a1, b1);
}

// 11) finalize (split logits + exact-chain fallback near ties)
__global__ __launch_bounds__(256) void finalize_k(const float* __restrict__ ue,
                                                  const float* __restrict__ W,
                                                  const float* __restrict__ b,
                                                  const float* __restrict__ g,
                                                  const int* __restrict__ nz,
                                                  const int* __restrict__ cand_i,
                                                  const int* __restrict__ cand_j,
                                                  const float* __restrict__ cand_v,
                                                  const float4* __restrict__ P,
                                                  float* __restrict__ out) {
  int p = blockIdx.x * 256 + threadIdx.x;
  if (p >= NTOT) return;

  int i, j;
  float wgt;
  if (p < EDGES) {
    i = nz[2 * p];
    j = nz[2 * p + 1];
    wgt = 1.0f;
  } else {
    int q = p - EDGES;
    i = cand_i[q];
    j = cand_j[q];
    wgt = fmaxf(cand_v[q], 0.0f);
  }

  float4 Pi = P[i], Pj = P[j];
  float l0 = Pi.x + Pj.y + b[0];
  float l1 = Pi.z + Pj.w + b[1];
  float g0 = g[2 * p], g1 = g[2 * p + 1];
  float s0 = l0 + g0, s1 = l1 + g1;

  if (fabsf(s0 - s1) < LOGIT_MARGIN) {
    const float* ri = ue + (size_t)i * DIMS;
    const float* rj = ue + (size_t)j * DIMS;
    float e0 = 0.f, e1 = 0.f;
    for (int k = 0; k < DIMS; ++k) {
      e0 = fmaf(ri[k], W[k], e0);
      e1 = fmaf(ri[k], W[256 + k], e1);
    }
    for (int k = 0; k < DIMS; ++k) {
      e0 = fmaf(rj[k], W[128 + k], e0);
      e1 = fmaf(rj[k], W[384 + k], e1);
    }
    s0 = (e0 + b[0]) + g0;
    s1 = (e1 + b[1]) + g1;
  }

  float w = (s0 >= s1) ? wgt : 0.0f;

  out[p] = w;
  out[NTOT + p] = w;
  out[2 * NTOT + p] = w;
  out[3 * NTOT + 2 * p + 0] = (float)i;
  out[3 * NTOT + 2 * p + 1] = (float)j;
}

// ---------------------------------------------------------------------------
extern "C" void kernel_launch(void* const* d_in, const int* in_sizes, int n_in,
                              void* d_out, int out_size, void* d_ws, size_t ws_size,
                              hipStream_t stream) {
  (void)in_sizes; (void)n_in; (void)out_size; (void)ws_size;

  const float* user_emb = (const float*)d_in[0];
  const float* W        = (const float*)d_in[1];
  const float* b        = (const float*)d_in[2];
  const float* gnoise   = (const float*)d_in[3];
  const int*   nz       = (const int*)d_in[4];
  float* out = (float*)d_out;

  char* ws = (char*)d_ws;
  float*          un       = (float*)(ws + 0);                        // 4 MB
  unsigned short* u0       = (unsigned short*)(ws + (4u << 20));      // 2 MB
  unsigned*       excl     = (unsigned*)(ws + (6u << 20));            // 8 MB
  unsigned*       list_key = (unsigned*)(ws + (14u << 20));           // 512 KB
  float*          list_v   = (float*)(ws + (14u << 20) + (512u << 10));
  int*            gcount   = (int*)(ws + (15u << 20));                // 4 B
  int*            row_cnt  = (int*)(ws + (15u << 20) + (4u << 10));   // 32 KB
  int*            row_off  = (int*)(ws + (15u << 20) + (40u << 10));  // 32.8 KB
  int*            row_pos  = (int*)(ws + (15u << 20) + (80u << 10));  // 32 KB
  int*            cand_i   = (int*)(ws + (16u << 20));                // 512 KB
  int*            cand_j   = (int*)(ws + (16u << 20) + (512u << 10)); // 512 KB
  float*          cand_v   = (float*)(ws + (17u << 20));              // 512 KB
  float4*         P        = (float4*)(ws + (17u << 20) + (512u << 10)); // 128 KB

  hipMemsetAsync(excl, 0, (size_t)N_USERS * 256 * sizeof(unsigned), stream);
  hipMemsetAsync(gcount, 0, sizeof(int), stream);
  hipMemsetAsync(row_cnt, 0, (size_t)N_USERS * sizeof(int), stream);
  hipMemsetAsync(row_pos, 0, (size_t)N_USERS * sizeof(int), stream);

  normalize_k<<<N_USERS / 256, 256, 0, stream>>>(user_emb, un, u0);
  build_excl<<<EDGES / 256, 256, 0, stream>>>(nz, excl);
  wprep_k<<<N_USERS / 256, 256, 0, stream>>>(user_emb, W, P);
  mfma_pass<<<2080, 256, 0, stream>>>(u0, list_key, list_v, gcount);
  resolve_k<<<LISTCAP / 256, 256, 0, stream>>>(un, excl, list_key, list_v, gcount);
  hist_k<<<LISTCAP / 256, 256, 0, stream>>>(list_key, gcount, row_cnt);
  scan8k<<<1, 256, 0, stream>>>(row_cnt, row_off);
  scatter_k<<<LISTCAP / 256, 256, 0, stream>>>(list_key, list_v, gcount,
                                               row_off, row_pos,
                                               cand_i, cand_j, cand_v);
  sortrow_k<<<N_USERS / 256, 256, 0, stream>>>(row_off, row_cnt, cand_j, cand_v);
  pad_k<<<KCAND / 256, 256, 0, stream>>>(row_off, cand_i, cand_j, cand_v);
  finalize_k<<<NTOT / 256, 256, 0, stream>>>(user_emb, W, b, gnoise, nz,
                                             cand_i, cand_j, cand_v, P, out);
}

// Round 8
// 205.079 us; speedup vs baseline: 5.5516x; 1.0290x over previous
//
#include <hip/hip_runtime.h>
#include <hip/hip_bf16.h>
#include <math.h>

#define N_USERS 8192
#define DIMS    128
#define EDGES   262144
#define KCAND   131072
#define NTOT    (EDGES + KCAND)      // 393216
#define LISTCAP 131072
#define CAPB    512                  // per-block LDS staging capacity
#define COS_THR 0.3f
#define EPS_SEL 6e-3f                // > hard error bound ~4e-3 of bf16 cos
#define LOGIT_MARGIN 2e-3f
#define DEADKEY 0xFFFFFFFFu

typedef short bf16x8 __attribute__((ext_vector_type(8)));
typedef float f32x4  __attribute__((ext_vector_type(4)));

// ---------------------------------------------------------------------------
// 1) normalize (bit-exact vs numpy) + bf16 copy + per-user partial logits
//    (fused: both passes read the same user row)
// ---------------------------------------------------------------------------
__global__ __launch_bounds__(256) void norm_wprep_k(const float* __restrict__ x,
                                                    const float* __restrict__ W,
                                                    float* __restrict__ un,
                                                    unsigned short* __restrict__ u0,
                                                    float4* __restrict__ P) {
#pragma clang fp contract(off)
  int i = blockIdx.x * 256 + threadIdx.x;
  if (i >= N_USERS) return;
  const float* r = x + (size_t)i * DIMS;
  float a[8];
#pragma unroll
  for (int j = 0; j < 8; ++j) { float t = r[j]; a[j] = t * t; }
  for (int b8 = 8; b8 < DIMS; b8 += 8) {
#pragma unroll
    for (int j = 0; j < 8; ++j) { float t = r[b8 + j]; a[j] = a[j] + t * t; }
  }
  float s = ((a[0] + a[1]) + (a[2] + a[3])) + ((a[4] + a[5]) + (a[6] + a[7]));
  float n = (float)sqrt((double)s);
  n = fmaxf(n, 1e-12f);
  for (int k = 0; k < DIMS; ++k) {
    float t = r[k] / n;
    un[(size_t)i * DIMS + k] = t;
    __hip_bfloat16 h = __float2bfloat16(t);
    u0[(size_t)i * DIMS + k] = *(unsigned short*)&h;
  }
  // partial logits from RAW user_emb rows (sequential fmaf — matches split use)
  float a0 = 0.f, b0 = 0.f, a1 = 0.f, b1 = 0.f;
  for (int k = 0; k < DIMS; ++k) {
    float t = r[k];
    a0 = fmaf(t, W[k], a0);
    b0 = fmaf(t, W[128 + k], b0);
    a1 = fmaf(t, W[256 + k], a1);
    b1 = fmaf(t, W[384 + k], b1);
  }
  P[i] = make_float4(a0, b0, a1, b1);
}

// ---------------------------------------------------------------------------
// 2) exclusion bitmask (8192 x 256 words)
// ---------------------------------------------------------------------------
__global__ __launch_bounds__(256) void build_excl(const int* __restrict__ nz,
                                                  unsigned* __restrict__ excl) {
  int t = blockIdx.x * 256 + threadIdx.x;
  if (t >= EDGES) return;
  int i = nz[2 * t], j = nz[2 * t + 1];
  atomicOr(&excl[(size_t)i * 256 + (j >> 5)], 1u << (j & 31));
}

// ---------------------------------------------------------------------------
// 3) mfma_pass: triangular sweep, block tile 128(I) x 64(J), J0 >= I0
//    (4160 blocks).  R7 post-mortem: 64 MB WRITE_SIZE = acc-tile spill to
//    scratch (peak live ~135 regs > 128 budget).  R8: wave tile 64x32 ->
//    acc 8 f32x4 = 32 regs, peak live ~90 -> no spill.
//    Emit rule: only j > i, plus mirror (j,i) — every ordered pair exactly
//    once (row/col tiles partition; floor(b/64) >= 2*floor(a/128) for a<b).
//    Epilogue: LDS staging list, ONE global atomicAdd per block.
// ---------------------------------------------------------------------------
__global__ __launch_bounds__(256) void mfma_pass(const unsigned short* __restrict__ u0,
                                                 unsigned* __restrict__ list_key,
                                                 float* __restrict__ list_v,
                                                 int* __restrict__ gcount) {
  __shared__ __align__(16) unsigned short As[4][128][8];  // 8 KB
  __shared__ __align__(16) unsigned short Bs[4][64][8];   // 4 KB
  __shared__ unsigned skey[CAPB];                         // 2 KB
  __shared__ float    sval[CAPB];                         // 2 KB
  __shared__ int lcnt, lbase;

  const int tid  = threadIdx.x;
  const int lane = tid & 63;
  const int wv   = tid >> 6;
  const int quad = lane >> 4;
  const int l15  = lane & 15;

  // triangular decode over (bi: 64 row-tiles of 128, bj: 128 col-tiles of 64)
  int rem = blockIdx.x, bi = 0;
  while (rem >= 128 - 2 * bi) { rem -= 128 - 2 * bi; ++bi; }
  const int bj = 2 * bi + rem;
  const int I0 = bi * 128, J0 = bj * 64;
  const int moff = (wv & 1) * 64, noff = (wv >> 1) * 32;

  if (tid == 0) lcnt = 0;

  f32x4 acc[4][2];
#pragma unroll
  for (int mt = 0; mt < 4; ++mt)
#pragma unroll
    for (int nt = 0; nt < 2; ++nt)
#pragma unroll
      for (int g = 0; g < 4; ++g) acc[mt][nt][g] = 0.f;

  uint4 pA[2], pB;
#define PF(KC)                                                                \
  {                                                                           \
    _Pragma("unroll")                                                         \
    for (int it = 0; it < 2; ++it) {                                          \
      int d = it * 256 + tid;                                                 \
      int row = d & 127, qd = d >> 7;                                         \
      pA[it] = *(const uint4*)((const char*)u0 +                              \
                (size_t)(I0 + row) * 256 + (KC) * 64 + qd * 16);              \
    }                                                                         \
    {                                                                         \
      int row = tid & 63, qd = tid >> 6;                                      \
      pB = *(const uint4*)((const char*)u0 +                                  \
                (size_t)(J0 + row) * 256 + (KC) * 64 + qd * 16);              \
    }                                                                         \
  }

  PF(0)

#pragma unroll 1
  for (int kc = 0; kc < 4; ++kc) {
    __syncthreads();
#pragma unroll
    for (int it = 0; it < 2; ++it) ((uint4*)As)[it * 256 + tid] = pA[it];
    ((uint4*)Bs)[tid] = pB;
    __syncthreads();
    if (kc < 3) PF(kc + 1)

    bf16x8 af[4], bfr[2];
#pragma unroll
    for (int mt = 0; mt < 4; ++mt)
      af[mt] = *(const bf16x8*)&As[quad][moff + mt * 16 + l15][0];
#pragma unroll
    for (int nt = 0; nt < 2; ++nt)
      bfr[nt] = *(const bf16x8*)&Bs[quad][noff + nt * 16 + l15][0];
#pragma unroll
    for (int mt = 0; mt < 4; ++mt)
#pragma unroll
      for (int nt = 0; nt < 2; ++nt)
        acc[mt][nt] = __builtin_amdgcn_mfma_f32_16x16x32_bf16(
            af[mt], bfr[nt], acc[mt][nt], 0, 0, 0);
  }
#undef PF

  // epilogue: j > i only; emit pair + mirror with one LDS atomic
#pragma unroll
  for (int mt = 0; mt < 4; ++mt)
#pragma unroll
    for (int nt = 0; nt < 2; ++nt)
#pragma unroll
      for (int g = 0; g < 4; ++g) {
        float v = acc[mt][nt][g];
        if (v > COS_THR - EPS_SEL) {
          int i = I0 + moff + mt * 16 + quad * 4 + g;
          int j = J0 + noff + nt * 16 + l15;
          if (j > i) {
            int idx = atomicAdd(&lcnt, 2);
            if (idx + 1 < CAPB) {
              skey[idx]     = ((unsigned)i << 13) | j;
              sval[idx]     = v;
              skey[idx + 1] = ((unsigned)j << 13) | i;
              sval[idx + 1] = v;
            }
          }
        }
      }

  __syncthreads();
  int n = min(lcnt, CAPB);
  if (tid == 0) lbase = atomicAdd(gcount, n);
  __syncthreads();
  int base = lbase;
  for (int t = tid; t < n; t += 256) {
    int o = base + t;
    if (o < LISTCAP) { list_key[o] = skey[t]; list_v[o] = sval[t]; }
  }
}

// ---------------------------------------------------------------------------
// 4) resolve + histogram (fused): excl/diag filter; borderline entries get
//    the exact sequential-fmaf chain; live entries bump row_cnt.
// ---------------------------------------------------------------------------
__global__ __launch_bounds__(256) void resolve_hist_k(const float* __restrict__ un,
                                                      const unsigned* __restrict__ excl,
                                                      unsigned* __restrict__ list_key,
                                                      float* __restrict__ list_v,
                                                      const int* __restrict__ gcount,
                                                      int* __restrict__ row_cnt) {
  int t = blockIdx.x * 256 + threadIdx.x;
  int n = min(*gcount, LISTCAP);
  if (t >= n) return;
  unsigned key = list_key[t];
  int i = key >> 13, j = key & 8191;
  unsigned word = excl[(size_t)i * 256 + (j >> 5)];
  bool alive = !(i == j || ((word >> (j & 31)) & 1u));
  if (alive && list_v[t] <= COS_THR + EPS_SEL) {   // borderline: decide exactly
    const float* a = un + (size_t)i * DIMS;
    const float* b = un + (size_t)j * DIMS;
    float s = 0.f;
    for (int k = 0; k < DIMS; ++k) s = fmaf(a[k], b[k], s);
    alive = (s > COS_THR);
    if (alive) list_v[t] = s;
  }
  if (!alive) list_key[t] = DEADKEY;
  else        atomicAdd(&row_cnt[i], 1);
}

// 5) exclusive scan over 8192 row counts (single block)
__global__ __launch_bounds__(256) void scan8k(const int* __restrict__ cnt,
                                              int* __restrict__ off) {
  __shared__ int sm[256];
  int t = threadIdx.x;
  int base = t * 32;
  int s = 0;
  for (int i = 0; i < 32; ++i) s += cnt[base + i];
  sm[t] = s;
  __syncthreads();
  int x = s;
  for (int d = 1; d < 256; d <<= 1) {
    int y = (t >= d) ? sm[t - d] : 0;
    __syncthreads();
    x += y;
    sm[t] = x;
    __syncthreads();
  }
  int run = x - s;
  for (int i = 0; i < 32; ++i) { off[base + i] = run; run += cnt[base + i]; }
  if (t == 255) off[N_USERS] = x;
}

// ---------------------------------------------------------------------------
// 6) scatter + pad (fused): live entries to per-row spans; tail [M,K) gets
//    pair (0,0), cos[0,0] = -1.  Pad slots (>= M) never collide with
//    scatter targets (< M).
// ---------------------------------------------------------------------------
__global__ __launch_bounds__(256) void scatter_pad_k(const unsigned* __restrict__ list_key,
                                                     const float* __restrict__ list_v,
                                                     const int* __restrict__ gcount,
                                                     const int* __restrict__ row_off,
                                                     int* __restrict__ row_pos,
                                                     int* __restrict__ cand_i,
                                                     int* __restrict__ cand_j,
                                                     float* __restrict__ cand_v) {
  int t = blockIdx.x * 256 + threadIdx.x;
  int n = min(*gcount, LISTCAP);
  int M = row_off[N_USERS];
  if (t < n) {
    unsigned key = list_key[t];
    if (key != DEADKEY) {
      int i = key >> 13, j = key & 8191;
      int pos = row_off[i] + atomicAdd(&row_pos[i], 1);
      if (pos < KCAND) {
        cand_i[pos] = i;
        cand_j[pos] = j;
        cand_v[pos] = list_v[t];
      }
    }
  }
  if (t >= M && t < KCAND) { cand_i[t] = 0; cand_j[t] = 0; cand_v[t] = -1.0f; }
}

// 7) sort each row's span ascending by j
__global__ __launch_bounds__(256) void sortrow_k(const int* __restrict__ row_off,
                                                 const int* __restrict__ row_cnt,
                                                 int* __restrict__ cand_j,
                                                 float* __restrict__ cand_v) {
  int r = blockIdx.x * 256 + threadIdx.x;
  if (r >= N_USERS) return;
  int o = row_off[r], c = row_cnt[r];
  if (o + c > KCAND) c = max(0, KCAND - o);
  for (int a = 1; a < c; ++a) {
    int jv = cand_j[o + a];
    float vv = cand_v[o + a];
    int b = a - 1;
    while (b >= 0 && cand_j[o + b] > jv) {
      cand_j[o + b + 1] = cand_j[o + b];
      cand_v[o + b + 1] = cand_v[o + b];
      --b;
    }
    cand_j[o + b + 1] = jv;
    cand_v[o + b + 1] = vv;
  }
}

// 8) finalize (split logits + exact-chain fallback near ties)
__global__ __launch_bounds__(256) void finalize_k(const float* __restrict__ ue,
                                                  const float* __restrict__ W,
                                                  const float* __restrict__ b,
                                                  const float* __restrict__ g,
                                                  const int* __restrict__ nz,
                                                  const int* __restrict__ cand_i,
                                                  const int* __restrict__ cand_j,
                                                  const float* __restrict__ cand_v,
                                                  const float4* __restrict__ P,
                                                  float* __restrict__ out) {
  int p = blockIdx.x * 256 + threadIdx.x;
  if (p >= NTOT) return;

  int i, j;
  float wgt;
  if (p < EDGES) {
    i = nz[2 * p];
    j = nz[2 * p + 1];
    wgt = 1.0f;
  } else {
    int q = p - EDGES;
    i = cand_i[q];
    j = cand_j[q];
    wgt = fmaxf(cand_v[q], 0.0f);
  }

  float4 Pi = P[i], Pj = P[j];
  float l0 = Pi.x + Pj.y + b[0];
  float l1 = Pi.z + Pj.w + b[1];
  float g0 = g[2 * p], g1 = g[2 * p + 1];
  float s0 = l0 + g0, s1 = l1 + g1;

  if (fabsf(s0 - s1) < LOGIT_MARGIN) {
    const float* ri = ue + (size_t)i * DIMS;
    const float* rj = ue + (size_t)j * DIMS;
    float e0 = 0.f, e1 = 0.f;
    for (int k = 0; k < DIMS; ++k) {
      e0 = fmaf(ri[k], W[k], e0);
      e1 = fmaf(ri[k], W[256 + k], e1);
    }
    for (int k = 0; k < DIMS; ++k) {
      e0 = fmaf(rj[k], W[128 + k], e0);
      e1 = fmaf(rj[k], W[384 + k], e1);
    }
    s0 = (e0 + b[0]) + g0;
    s1 = (e1 + b[1]) + g1;
  }

  float w = (s0 >= s1) ? wgt : 0.0f;

  out[p] = w;
  out[NTOT + p] = w;
  out[2 * NTOT + p] = w;
  out[3 * NTOT + 2 * p + 0] = (float)i;
  out[3 * NTOT + 2 * p + 1] = (float)j;
}

// ---------------------------------------------------------------------------
extern "C" void kernel_launch(void* const* d_in, const int* in_sizes, int n_in,
                              void* d_out, int out_size, void* d_ws, size_t ws_size,
                              hipStream_t stream) {
  (void)in_sizes; (void)n_in; (void)out_size; (void)ws_size;

  const float* user_emb = (const float*)d_in[0];
  const float* W        = (const float*)d_in[1];
  const float* b        = (const float*)d_in[2];
  const float* gnoise   = (const float*)d_in[3];
  const int*   nz       = (const int*)d_in[4];
  float* out = (float*)d_out;

  char* ws = (char*)d_ws;
  float*          un       = (float*)(ws + 0);                        // 4 MB
  unsigned short* u0       = (unsigned short*)(ws + (4u << 20));      // 2 MB
  unsigned*       excl     = (unsigned*)(ws + (6u << 20));            // 8 MB
  unsigned*       list_key = (unsigned*)(ws + (14u << 20));           // 512 KB
  float*          list_v   = (float*)(ws + (14u << 20) + (512u << 10));
  // contiguous zeroed counter region: gcount | row_cnt | row_pos
  char*           zbase    = ws + (15u << 20);
  int*            gcount   = (int*)(zbase);                           // 64 B slot
  int*            row_cnt  = (int*)(zbase + 64);                      // 32 KB
  int*            row_pos  = (int*)(zbase + 64 + 32768);              // 32 KB
  int*            row_off  = (int*)(zbase + 64 + 65536);              // 32.8 KB
  int*            cand_i   = (int*)(ws + (16u << 20));                // 512 KB
  int*            cand_j   = (int*)(ws + (16u << 20) + (512u << 10)); // 512 KB
  float*          cand_v   = (float*)(ws + (17u << 20));              // 512 KB
  float4*         P        = (float4*)(ws + (17u << 20) + (512u << 10)); // 128 KB

  hipMemsetAsync(excl, 0, (size_t)N_USERS * 256 * sizeof(unsigned), stream);
  hipMemsetAsync(zbase, 0, 64 + 2 * 32768, stream);

  norm_wprep_k<<<N_USERS / 256, 256, 0, stream>>>(user_emb, W, un, u0, P);
  build_excl<<<EDGES / 256, 256, 0, stream>>>(nz, excl);
  mfma_pass<<<4160, 256, 0, stream>>>(u0, list_key, list_v, gcount);
  resolve_hist_k<<<LISTCAP / 256, 256, 0, stream>>>(un, excl, list_key, list_v,
                                                    gcount, row_cnt);
  scan8k<<<1, 256, 0, stream>>>(row_cnt, row_off);
  scatter_pad_k<<<KCAND / 256, 256, 0, stream>>>(list_key, list_v, gcount,
                                                 row_off, row_pos,
                                                 cand_i, cand_j, cand_v);
  sortrow_k<<<N_USERS / 256, 256, 0, stream>>>(row_off, row_cnt, cand_j, cand_v);
  finalize_k<<<NTOT / 256, 256, 0, stream>>>(user_emb, W, b, gnoise, nz,
                                             cand_i, cand_j, cand_v, P, out);
}

// Round 9
// 178.335 us; speedup vs baseline: 6.3841x; 1.1500x over previous
//
#include <hip/hip_runtime.h>
#include <hip/hip_bf16.h>
#include <math.h>

#define N_USERS 8192
#define DIMS    128
#define EDGES   262144
#define KCAND   131072
#define NTOT    (EDGES + KCAND)      // 393216
#define LISTCAP 131072
#define CAPB    512                  // per-block LDS staging capacity (entries)
#define COS_THR 0.3f
#define EPS_SEL 6e-3f                // > hard error bound ~4e-3 of bf16 cos
#define LOGIT_MARGIN 2e-3f
#define DEADKEY 0xFFFFFFFFu

typedef short bf16x8 __attribute__((ext_vector_type(8)));
typedef float f32x4  __attribute__((ext_vector_type(4)));

// ---------------------------------------------------------------------------
// 1) normalize (bit-exact vs numpy) + bf16 copy + per-user partial logits
// ---------------------------------------------------------------------------
__global__ __launch_bounds__(256) void norm_wprep_k(const float* __restrict__ x,
                                                    const float* __restrict__ W,
                                                    float* __restrict__ un,
                                                    unsigned short* __restrict__ u0,
                                                    float4* __restrict__ P) {
#pragma clang fp contract(off)
  int i = blockIdx.x * 256 + threadIdx.x;
  if (i >= N_USERS) return;
  const float* r = x + (size_t)i * DIMS;
  float a[8];
#pragma unroll
  for (int j = 0; j < 8; ++j) { float t = r[j]; a[j] = t * t; }
  for (int b8 = 8; b8 < DIMS; b8 += 8) {
#pragma unroll
    for (int j = 0; j < 8; ++j) { float t = r[b8 + j]; a[j] = a[j] + t * t; }
  }
  float s = ((a[0] + a[1]) + (a[2] + a[3])) + ((a[4] + a[5]) + (a[6] + a[7]));
  float n = (float)sqrt((double)s);
  n = fmaxf(n, 1e-12f);
  for (int k = 0; k < DIMS; ++k) {
    float t = r[k] / n;
    un[(size_t)i * DIMS + k] = t;
    __hip_bfloat16 h = __float2bfloat16(t);
    u0[(size_t)i * DIMS + k] = *(unsigned short*)&h;
  }
  float a0 = 0.f, b0 = 0.f, a1 = 0.f, b1 = 0.f;
  for (int k = 0; k < DIMS; ++k) {
    float t = r[k];
    a0 = fmaf(t, W[k], a0);
    b0 = fmaf(t, W[128 + k], b0);
    a1 = fmaf(t, W[256 + k], a1);
    b1 = fmaf(t, W[384 + k], b1);
  }
  P[i] = make_float4(a0, b0, a1, b1);
}

// ---------------------------------------------------------------------------
// 2) exclusion bitmask (8192 x 256 words)
// ---------------------------------------------------------------------------
__global__ __launch_bounds__(256) void build_excl(const int* __restrict__ nz,
                                                  unsigned* __restrict__ excl) {
  int t = blockIdx.x * 256 + threadIdx.x;
  if (t >= EDGES) return;
  int i = nz[2 * t], j = nz[2 * t + 1];
  atomicOr(&excl[(size_t)i * 256 + (j >> 5)], 1u << (j & 31));
}

// ---------------------------------------------------------------------------
// 3) mfma_pass: 128x128 tiles, triangular (bJ >= bI, 2080 blocks of 512).
//    R8 post-mortem: per-block barrier-round latency dominated (4 stage
//    rounds x 2 barriers around ~40cyc compute; all pipes idle).  R9:
//    SINGLE-SHOT K staging — whole K=128 of both tiles in LDS (64 KB),
//    ONE barrier, then 32 MFMAs/wave uninterrupted.  8 waves, wave tile
//    32x64 -> acc 32 VGPRs (no spill, R8-verified budget).
//    LDS layout [kc][quad][row][8] — R7-measured conflict-free for both
//    flat staging writes and b128 fragment reads.
//    Emit j>i + mirror; LDS list; ONE global atomicAdd per block.
// ---------------------------------------------------------------------------
__global__ __launch_bounds__(512) void mfma_pass(const unsigned short* __restrict__ u0,
                                                 uint2* __restrict__ list,
                                                 int* __restrict__ gcount) {
  __shared__ __align__(16) unsigned short As[4][4][128][8];  // 32 KB
  __shared__ __align__(16) unsigned short Bs[4][4][128][8];  // 32 KB
  __shared__ uint2 svec[CAPB];                               // 4 KB
  __shared__ int lcnt, lbase;

  const int tid  = threadIdx.x;
  const int lane = tid & 63;
  const int wv   = tid >> 6;
  const int quad = lane >> 4;
  const int l15  = lane & 15;

  // triangular decode: (bi, bj) with bj >= bi over 64 tiles of 128
  int rem = blockIdx.x, bi = 0;
  while (rem >= 64 - bi) { rem -= 64 - bi; ++bi; }
  const int bj = bi + rem;
  const int I0 = bi * 128, J0 = bj * 128;
  const int moff = (wv & 3) * 32, noff = (wv >> 2) * 64;

  if (tid == 0) lcnt = 0;

  // ---- single-shot staging: 4 A-chunks + 4 B-chunks per thread ----
  uint4 pA[4], pB[4];
#pragma unroll
  for (int it = 0; it < 4; ++it) {
    int f = it * 512 + tid;           // 0..2047
    int row = f & 127, cq = f >> 7;   // cq = kc*4+quad
    pA[it] = *(const uint4*)((const char*)u0 +
              (size_t)(I0 + row) * 256 + cq * 16);
    pB[it] = *(const uint4*)((const char*)u0 +
              (size_t)(J0 + row) * 256 + cq * 16);
  }
#pragma unroll
  for (int it = 0; it < 4; ++it) {
    ((uint4*)As)[it * 512 + tid] = pA[it];
    ((uint4*)Bs)[it * 512 + tid] = pB[it];
  }
  __syncthreads();   // the ONLY barrier before the epilogue

  f32x4 acc[2][4];
#pragma unroll
  for (int mt = 0; mt < 2; ++mt)
#pragma unroll
    for (int nt = 0; nt < 4; ++nt)
#pragma unroll
      for (int g = 0; g < 4; ++g) acc[mt][nt][g] = 0.f;

  // ---- K loop: 4 kc x (2 af + 4 bfr b128 reads, 8 MFMAs), no barriers ----
#pragma unroll
  for (int kc = 0; kc < 4; ++kc) {
    bf16x8 af[2], bfr[4];
#pragma unroll
    for (int mt = 0; mt < 2; ++mt)
      af[mt] = *(const bf16x8*)&As[kc][quad][moff + mt * 16 + l15][0];
#pragma unroll
    for (int nt = 0; nt < 4; ++nt)
      bfr[nt] = *(const bf16x8*)&Bs[kc][quad][noff + nt * 16 + l15][0];
#pragma unroll
    for (int mt = 0; mt < 2; ++mt)
#pragma unroll
      for (int nt = 0; nt < 4; ++nt)
        acc[mt][nt] = __builtin_amdgcn_mfma_f32_16x16x32_bf16(
            af[mt], bfr[nt], acc[mt][nt], 0, 0, 0);
  }

  // ---- epilogue: j > i only; emit pair + mirror (one LDS atomic) ----
#pragma unroll
  for (int mt = 0; mt < 2; ++mt)
#pragma unroll
    for (int nt = 0; nt < 4; ++nt)
#pragma unroll
      for (int g = 0; g < 4; ++g) {
        float v = acc[mt][nt][g];
        if (v > COS_THR - EPS_SEL) {
          int i = I0 + moff + mt * 16 + quad * 4 + g;
          int j = J0 + noff + nt * 16 + l15;
          if (j > i) {
            int idx = atomicAdd(&lcnt, 2);
            if (idx + 1 < CAPB) {
              svec[idx]     = make_uint2(((unsigned)i << 13) | j,
                                         __float_as_uint(v));
              svec[idx + 1] = make_uint2(((unsigned)j << 13) | i,
                                         __float_as_uint(v));
            }
          }
        }
      }

  __syncthreads();
  int n = min(lcnt, CAPB);
  if (tid == 0) lbase = atomicAdd(gcount, n);
  __syncthreads();
  int base = lbase;
  for (int t = tid; t < n; t += 512) {
    int o = base + t;
    if (o < LISTCAP) list[o] = svec[t];
  }
}

// ---------------------------------------------------------------------------
// 4) resolve + histogram (fused): excl/diag filter; borderline entries get
//    the exact sequential-fmaf chain; live entries bump row_cnt.
// ---------------------------------------------------------------------------
__global__ __launch_bounds__(256) void resolve_hist_k(const float* __restrict__ un,
                                                      const unsigned* __restrict__ excl,
                                                      uint2* __restrict__ list,
                                                      const int* __restrict__ gcount,
                                                      int* __restrict__ row_cnt) {
  int t = blockIdx.x * 256 + threadIdx.x;
  int n = min(*gcount, LISTCAP);
  if (t >= n) return;
  uint2 e = list[t];
  int i = e.x >> 13, j = e.x & 8191;
  unsigned word = excl[(size_t)i * 256 + (j >> 5)];
  bool alive = !(i == j || ((word >> (j & 31)) & 1u));
  float v = __uint_as_float(e.y);
  if (alive && v <= COS_THR + EPS_SEL) {   // borderline: decide exactly
    const float* a = un + (size_t)i * DIMS;
    const float* b = un + (size_t)j * DIMS;
    float s = 0.f;
    for (int k = 0; k < DIMS; ++k) s = fmaf(a[k], b[k], s);
    alive = (s > COS_THR);
    if (alive) list[t] = make_uint2(e.x, __float_as_uint(s));
  }
  if (!alive) list[t] = make_uint2(DEADKEY, 0u);
  else        atomicAdd(&row_cnt[i], 1);
}

// 5) exclusive scan over 8192 row counts (single block)
__global__ __launch_bounds__(256) void scan8k(const int* __restrict__ cnt,
                                              int* __restrict__ off) {
  __shared__ int sm[256];
  int t = threadIdx.x;
  int base = t * 32;
  int s = 0;
  for (int i = 0; i < 32; ++i) s += cnt[base + i];
  sm[t] = s;
  __syncthreads();
  int x = s;
  for (int d = 1; d < 256; d <<= 1) {
    int y = (t >= d) ? sm[t - d] : 0;
    __syncthreads();
    x += y;
    sm[t] = x;
    __syncthreads();
  }
  int run = x - s;
  for (int i = 0; i < 32; ++i) { off[base + i] = run; run += cnt[base + i]; }
  if (t == 255) off[N_USERS] = x;
}

// ---------------------------------------------------------------------------
// 6) scatter + pad (fused)
// ---------------------------------------------------------------------------
__global__ __launch_bounds__(256) void scatter_pad_k(const uint2* __restrict__ list,
                                                     const int* __restrict__ gcount,
                                                     const int* __restrict__ row_off,
                                                     int* __restrict__ row_pos,
                                                     int* __restrict__ cand_i,
                                                     int* __restrict__ cand_j,
                                                     float* __restrict__ cand_v) {
  int t = blockIdx.x * 256 + threadIdx.x;
  int n = min(*gcount, LISTCAP);
  int M = row_off[N_USERS];
  if (t < n) {
    uint2 e = list[t];
    if (e.x != DEADKEY) {
      int i = e.x >> 13, j = e.x & 8191;
      int pos = row_off[i] + atomicAdd(&row_pos[i], 1);
      if (pos < KCAND) {
        cand_i[pos] = i;
        cand_j[pos] = j;
        cand_v[pos] = __uint_as_float(e.y);
      }
    }
  }
  if (t >= M && t < KCAND) { cand_i[t] = 0; cand_j[t] = 0; cand_v[t] = -1.0f; }
}

// 7) sort each row's span ascending by j
__global__ __launch_bounds__(256) void sortrow_k(const int* __restrict__ row_off,
                                                 const int* __restrict__ row_cnt,
                                                 int* __restrict__ cand_j,
                                                 float* __restrict__ cand_v) {
  int r = blockIdx.x * 256 + threadIdx.x;
  if (r >= N_USERS) return;
  int o = row_off[r], c = row_cnt[r];
  if (o + c > KCAND) c = max(0, KCAND - o);
  for (int a = 1; a < c; ++a) {
    int jv = cand_j[o + a];
    float vv = cand_v[o + a];
    int b = a - 1;
    while (b >= 0 && cand_j[o + b] > jv) {
      cand_j[o + b + 1] = cand_j[o + b];
      cand_v[o + b + 1] = cand_v[o + b];
      --b;
    }
    cand_j[o + b + 1] = jv;
    cand_v[o + b + 1] = vv;
  }
}

// 8) finalize (split logits + exact-chain fallback near ties)
__global__ __launch_bounds__(256) void finalize_k(const float* __restrict__ ue,
                                                  const float* __restrict__ W,
                                                  const float* __restrict__ b,
                                                  const float* __restrict__ g,
                                                  const int* __restrict__ nz,
                                                  const int* __restrict__ cand_i,
                                                  const int* __restrict__ cand_j,
                                                  const float* __restrict__ cand_v,
                                                  const float4* __restrict__ P,
                                                  float* __restrict__ out) {
  int p = blockIdx.x * 256 + threadIdx.x;
  if (p >= NTOT) return;

  int i, j;
  float wgt;
  if (p < EDGES) {
    i = nz[2 * p];
    j = nz[2 * p + 1];
    wgt = 1.0f;
  } else {
    int q = p - EDGES;
    i = cand_i[q];
    j = cand_j[q];
    wgt = fmaxf(cand_v[q], 0.0f);
  }

  float4 Pi = P[i], Pj = P[j];
  float l0 = Pi.x + Pj.y + b[0];
  float l1 = Pi.z + Pj.w + b[1];
  float g0 = g[2 * p], g1 = g[2 * p + 1];
  float s0 = l0 + g0, s1 = l1 + g1;

  if (fabsf(s0 - s1) < LOGIT_MARGIN) {
    const float* ri = ue + (size_t)i * DIMS;
    const float* rj = ue + (size_t)j * DIMS;
    float e0 = 0.f, e1 = 0.f;
    for (int k = 0; k < DIMS; ++k) {
      e0 = fmaf(ri[k], W[k], e0);
      e1 = fmaf(ri[k], W[256 + k], e1);
    }
    for (int k = 0; k < DIMS; ++k) {
      e0 = fmaf(rj[k], W[128 + k], e0);
      e1 = fmaf(rj[k], W[384 + k], e1);
    }
    s0 = (e0 + b[0]) + g0;
    s1 = (e1 + b[1]) + g1;
  }

  float w = (s0 >= s1) ? wgt : 0.0f;

  out[p] = w;
  out[NTOT + p] = w;
  out[2 * NTOT + p] = w;
  out[3 * NTOT + 2 * p + 0] = (float)i;
  out[3 * NTOT + 2 * p + 1] = (float)j;
}

// ---------------------------------------------------------------------------
extern "C" void kernel_launch(void* const* d_in, const int* in_sizes, int n_in,
                              void* d_out, int out_size, void* d_ws, size_t ws_size,
                              hipStream_t stream) {
  (void)in_sizes; (void)n_in; (void)out_size; (void)ws_size;

  const float* user_emb = (const float*)d_in[0];
  const float* W        = (const float*)d_in[1];
  const float* b        = (const float*)d_in[2];
  const float* gnoise   = (const float*)d_in[3];
  const int*   nz       = (const int*)d_in[4];
  float* out = (float*)d_out;

  char* ws = (char*)d_ws;
  float*          un      = (float*)(ws + 0);                        // 4 MB
  unsigned short* u0      = (unsigned short*)(ws + (4u << 20));      // 2 MB
  unsigned*       excl    = (unsigned*)(ws + (6u << 20));            // 8 MB
  uint2*          list    = (uint2*)(ws + (14u << 20));              // 1 MB
  // contiguous zeroed counter region: gcount | row_cnt | row_pos
  char*           zbase   = ws + (15u << 20);
  int*            gcount  = (int*)(zbase);                           // 64 B slot
  int*            row_cnt = (int*)(zbase + 64);                      // 32 KB
  int*            row_pos = (int*)(zbase + 64 + 32768);              // 32 KB
  int*            row_off = (int*)(zbase + 64 + 65536);              // 32.8 KB
  int*            cand_i  = (int*)(ws + (16u << 20));                // 512 KB
  int*            cand_j  = (int*)(ws + (16u << 20) + (512u << 10)); // 512 KB
  float*          cand_v  = (float*)(ws + (17u << 20));              // 512 KB
  float4*         P       = (float4*)(ws + (17u << 20) + (512u << 10)); // 128 KB

  hipMemsetAsync(excl, 0, (size_t)N_USERS * 256 * sizeof(unsigned), stream);
  hipMemsetAsync(zbase, 0, 64 + 2 * 32768, stream);

  norm_wprep_k<<<N_USERS / 256, 256, 0, stream>>>(user_emb, W, un, u0, P);
  build_excl<<<EDGES / 256, 256, 0, stream>>>(nz, excl);
  mfma_pass<<<2080, 512, 0, stream>>>(u0, list, gcount);
  resolve_hist_k<<<LISTCAP / 256, 256, 0, stream>>>(un, excl, list, gcount,
                                                    row_cnt);
  scan8k<<<1, 256, 0, stream>>>(row_cnt, row_off);
  scatter_pad_k<<<KCAND / 256, 256, 0, stream>>>(list, gcount, row_off, row_pos,
                                                 cand_i, cand_j, cand_v);
  sortrow_k<<<N_USERS / 256, 256, 0, stream>>>(row_off, row_cnt, cand_j, cand_v);
  finalize_k<<<NTOT / 256, 256, 0, stream>>>(user_emb, W, b, gnoise, nz,
                                             cand_i, cand_j, cand_v, P, out);
}